// Round 13
// baseline (1996.754 us; speedup 1.0000x reference)
//
#include <hip/hip_runtime.h>

#define NN 8000
#define EE 200000
#define EEP 200064
#define BB 16
#define DD 256
#define LL 4
#define KF 600
#define HEPAD 280
#define ASPAD 40

typedef unsigned short bf16;
typedef short bf16x8 __attribute__((ext_vector_type(8)));
typedef float f32x4 __attribute__((ext_vector_type(4)));

__device__ __forceinline__ float b2f(bf16 u) { return __uint_as_float(((unsigned)u) << 16); }
__device__ __forceinline__ bf16 f2b(float f) {
    unsigned u = __float_as_uint(f);
    u = u + 0x7fffu + ((u >> 16) & 1u);
    return (bf16)(u >> 16);
}

// sin/cos of 2*pi*d*f via v_sin/v_cos in revolutions: sin(2pi*t), t = fract(d*f)
__device__ __forceinline__ float fvalr(float d0, float d1, float d2, int j) {
    int jj = (j < 300) ? j : j - 300;
    int c = jj / 100;
    int f = jj - c * 100;
    float d = (c == 0) ? d0 : ((c == 1) ? d1 : d2);
    float t = d * (float)f;
    t = t - floorf(t);
    return (j < 300) ? __builtin_amdgcn_sinf(t) : __builtin_amdgcn_cosf(t);
}

// legacy radians version (fallback kernels)
__device__ __forceinline__ float fval(float d0, float d1, float d2, int j) {
    int jj = (j < 300) ? j : j - 300;
    int c = jj / 100;
    int f = jj - c * 100;
    float d = (c == 0) ? d0 : ((c == 1) ? d1 : d2);
    float ang = 6.283185307179586f * d * (float)f;
    return (j < 300) ? __sinf(ang) : __cosf(ang);
}

// b-fragment read from a swizzled 256x32 panel in LDS: n = t*16+m, kblk swizzled
__device__ __forceinline__ bf16x8 bfrag(const bf16* bsu, int t, int m, int quad) {
    int q2 = (quad + ((m >> 1) & 3)) & 3;
    return *(const bf16x8*)&bsu[(t * 16 + m) * 32 + q2 * 8];
}

// ---------------- setup ----------------

__global__ void k_lfeat(const float* __restrict__ lat, float* __restrict__ lf) {
    int t = threadIdx.x;
    if (t >= BB * 6) return;
    int b = t / 6, p = t % 6;
    const int rr[6] = {0, 0, 0, 1, 1, 2};
    const int cc[6] = {0, 1, 2, 1, 2, 2};
    float acc = 0.f;
    for (int i = 0; i < 3; i++)
        acc += lat[b * 9 + i * 3 + rr[p]] * lat[b * 9 + i * 3 + cc[p]];
    lf[b * 6 + p] = acc;
}

__global__ void k_zero(int* __restrict__ p, int n) {
    int i = blockIdx.x * 256 + threadIdx.x;
    if (i < n) p[i] = 0;
}

__global__ void k_zerof(float* __restrict__ p, int n) {
    int i = blockIdx.x * 256 + threadIdx.x;
    if (i < n) p[i] = 0.f;
}

__global__ void k_count(const int* __restrict__ src, int* __restrict__ counts) {
    int e = blockIdx.x * 256 + threadIdx.x;
    if (e < EE) atomicAdd(&counts[src[e]], 1);
}

__global__ void k_scan(const int* __restrict__ counts, int* __restrict__ starts,
                       int* __restrict__ cursor) {
    __shared__ int ssum[256];
    int tid = threadIdx.x;
    int base = tid * 32;
    int local = 0;
    for (int i = 0; i < 32; i++) {
        int r = base + i;
        if (r < NN) local += counts[r];
    }
    ssum[tid] = local;
    __syncthreads();
    for (int off = 1; off < 256; off <<= 1) {
        int v = (tid >= off) ? ssum[tid - off] : 0;
        __syncthreads();
        ssum[tid] += v;
        __syncthreads();
    }
    int run = (tid == 0) ? 0 : ssum[tid - 1];
    for (int i = 0; i < 32; i++) {
        int r = base + i;
        if (r < NN) {
            starts[r] = run;
            cursor[r] = run;
            run += counts[r];
        }
    }
    if (tid == 255) starts[NN] = ssum[255];
}

// scatter also emits CSR-permuted src/dst arrays
__global__ void k_scatter(const int* __restrict__ src, const int* __restrict__ dst,
                          int* __restrict__ cursor, int* __restrict__ eids,
                          int* __restrict__ srcP, int* __restrict__ dstP) {
    int e = blockIdx.x * 256 + threadIdx.x;
    if (e >= EE) return;
    int s = src[e];
    int pos = atomicAdd(&cursor[s], 1);
    eids[pos] = e;
    srcP[pos] = s;
    dstP[pos] = dst[e];
}

// init pad entries [EE, EEP): srcP/dstP = 0, heG pad rows = 0
__global__ void k_padinit(int* __restrict__ srcP, int* __restrict__ dstP,
                          bf16* __restrict__ heG) {
    int t = threadIdx.x;
    if (t < EEP - EE) {
        srcP[EE + t] = 0;
        dstP[EE + t] = 0;
    }
    for (int i = t; i < (EEP - EE) * 256; i += 256) heG[(size_t)EE * 256 + i] = 0;
}

__global__ void k_node_init(const int* __restrict__ at, const int* __restrict__ bid,
                            const float* __restrict__ emb, const float* __restrict__ W,
                            const float* __restrict__ nb, const float* __restrict__ lf,
                            float* __restrict__ hn, bf16* __restrict__ hb) {
    __shared__ float arow[262];
    int n = blockIdx.x, d = threadIdx.x;
    arow[d] = emb[at[n] * DD + d];
    if (d < 6) arow[256 + d] = lf[bid[n] * 6 + d];
    __syncthreads();
    float acc = nb[d];
    for (int k = 0; k < 262; k++) acc += arow[k] * W[k * DD + d];
    hn[n * DD + d] = acc;
    hb[n * DD + d] = f2b(acc);
}

__global__ void k_cvt(const float* __restrict__ src, bf16* __restrict__ dst, int n) {
    int i = blockIdx.x * 256 + threadIdx.x;
    if (i < n) dst[i] = f2b(src[i]);
}

// cat bias per layer: out[l][0:256]=bq, [256:768]=bkv
__global__ void k_catbias(const float* __restrict__ bq, const float* __restrict__ bkv,
                          float* __restrict__ out) {
    int l = blockIdx.x, t = threadIdx.x;
    out[l * 768 + t] = (t < 256) ? bq[l * 256 + t] : bkv[l * 512 + (t - 256)];
}

// ---------------- swizzled panel builder ----------------

__global__ void k_panel(const float* __restrict__ W, int ldw, int r0, int c0,
                        size_t wlstride, int Ktot, bf16* __restrict__ dst,
                        int pcount, int lstride) {
    int p = blockIdx.x, l = blockIdx.y, g = blockIdx.z, n = threadIdx.x;
    const float* Wl = W + (size_t)l * wlstride;
    bf16* d = dst + ((size_t)l * lstride + (size_t)g * pcount + p) * 8192;
    int c = c0 + g * 256 + n;
    for (int kk = 0; kk < 32; kk++) {
        int kl = p * 32 + kk;
        float v = (kl < Ktot) ? Wl[(size_t)(r0 + kl) * ldw + c] : 0.f;
        int swz = ((((kk >> 3) + ((n >> 1) & 3)) & 3)) * 8 + (kk & 7);
        d[n * 32 + swz] = f2b(v);
    }
}

// VWo[l][r][c] = sum_n Wv_lo[k][h*64+n] * Wo[h*64+n][c], r = h*256+k
__global__ void k_vwo(const float* __restrict__ Wkv, const float* __restrict__ Wo,
                      float* __restrict__ out) {
    int r = blockIdx.x, l = blockIdx.y, c = threadIdx.x;
    int h = r >> 8, k = r & 255;
    const float* wv = Wkv + (size_t)l * 512 * 512 + (size_t)(256 + k) * 512 + 256 + h * 64;
    const float* wo = Wo + (size_t)l * 256 * 256 + (size_t)(h * 64) * 256 + c;
    float acc = 0.f;
    for (int n = 0; n < 64; n++) acc += wv[n] * wo[(size_t)n * 256];
    out[((size_t)l * 1024 + r) * 256 + c] = acc;
}

// ---------------- he precompute (per-lane fvals, B double-buffered, 1 barrier/p) ----------
// round-8-proven form: separate heb + Bs[2]

__global__ void __launch_bounds__(256) k_he(
    const int* __restrict__ src, const int* __restrict__ dst,
    const int* __restrict__ eids,
    const float* __restrict__ frac, const float* __restrict__ shifts,
    const uint4* __restrict__ WeP, const float* __restrict__ be,
    bf16* __restrict__ heG) {
    __shared__ bf16 heb[64][HEPAD];
    __shared__ uint4 Bs[2][1024];
    __shared__ float dsv[64][3];

    int tid = threadIdx.x;
    int wv = tid >> 6, lane = tid & 63, quad = lane >> 4, m = lane & 15;
    int e0 = blockIdx.x * 64;
    if (tid < 64) {
        int e = eids ? eids[e0 + tid] : (e0 + tid);
        int sn = src[e], dn = dst[e];
#pragma unroll
        for (int c = 0; c < 3; c++) {
            float a = frac[dn * 3 + c] - frac[sn * 3 + c] + shifts[e * 3 + c];
            dsv[tid][c] = a - floorf(a);
        }
    }
#pragma unroll
    for (int i = 0; i < 4; i++) Bs[0][tid + i * 256] = WeP[tid + i * 256];
    __syncthreads();

    int row = 16 * wv + m;
    float d0 = dsv[row][0], d1 = dsv[row][1], d2 = dsv[row][2];

    f32x4 acc1[16];
#pragma unroll
    for (int t = 0; t < 16; t++) acc1[t] = (f32x4){0.f, 0.f, 0.f, 0.f};
    for (int p = 0; p < 19; p++) {
        if (p + 1 < 19) {
#pragma unroll
            for (int i = 0; i < 4; i++)
                Bs[(p + 1) & 1][tid + i * 256] = WeP[(size_t)(p + 1) * 1024 + tid + i * 256];
        }
        bf16 t8[8];
#pragma unroll
        for (int j = 0; j < 8; j++) {
            int k = p * 32 + quad * 8 + j;
            t8[j] = (k < KF) ? f2b(fvalr(d0, d1, d2, k)) : (bf16)0;
        }
        bf16x8 a = *(const bf16x8*)t8;
        const bf16* bsu = (const bf16*)Bs[p & 1];
#pragma unroll
        for (int t = 0; t < 16; t++)
            acc1[t] = __builtin_amdgcn_mfma_f32_16x16x32_bf16(a, bfrag(bsu, t, m, quad),
                                                              acc1[t], 0, 0, 0);
        __syncthreads();
    }
#pragma unroll
    for (int t = 0; t < 16; t++) {
        int col = t * 16 + m;
        float bias = be[col];
#pragma unroll
        for (int r = 0; r < 4; r++)
            heb[16 * wv + quad * 4 + r][col] = f2b(acc1[t][r] + bias);
    }
    __syncthreads();
#pragma unroll
    for (int i = 0; i < 8; i++) {
        int idx = tid * 8 + i;
        int rw = idx >> 5, c = idx & 31;
        *(uint4*)&heG[(size_t)(e0 + rw) * 256 + c * 8] = *(const uint4*)&heb[rw][c * 8];
    }
}

// ---------------- fused edge score kernel: 512 threads, 128 edges/block ----------------

__global__ void __launch_bounds__(512) k_qk3(
    const bf16* __restrict__ heG, const int* __restrict__ src, const int* __restrict__ dst,
    const float* __restrict__ nq, const uint4* __restrict__ EQP,
    const uint4* __restrict__ EKP, float* __restrict__ scores) {
    __shared__ uint4 Bs[2][2048];  // per buffer: Q panel [0,1024) + K panel [1024,2048)
    __shared__ int sid[128], did[128];
    int tid = threadIdx.x;
    int wv = tid >> 6, lane = tid & 63, quad = lane >> 4, m = lane & 15;
    int e0 = blockIdx.x * 128;
    if (tid < 128) {
        sid[tid] = src[e0 + tid];
        did[tid] = dst[e0 + tid];
    }
#pragma unroll
    for (int i = 0; i < 2; i++) {
        Bs[0][tid + i * 512] = EQP[tid + i * 512];
        Bs[0][1024 + tid + i * 512] = EKP[tid + i * 512];
    }
    __syncthreads();
    int arow = e0 + 16 * wv + m;
    f32x4 qa[16], ka[16];
#pragma unroll
    for (int t = 0; t < 16; t++) {
        qa[t] = (f32x4){0.f, 0.f, 0.f, 0.f};
        ka[t] = (f32x4){0.f, 0.f, 0.f, 0.f};
    }
    for (int p = 0; p < 8; p++) {
        if (p + 1 < 8) {
#pragma unroll
            for (int i = 0; i < 2; i++) {
                Bs[(p + 1) & 1][tid + i * 512] = EQP[(size_t)(p + 1) * 1024 + tid + i * 512];
                Bs[(p + 1) & 1][1024 + tid + i * 512] =
                    EKP[(size_t)(p + 1) * 1024 + tid + i * 512];
            }
        }
        bf16x8 a = *(const bf16x8*)&heG[(size_t)arow * 256 + p * 32 + quad * 8];
        const bf16* bsu = (const bf16*)Bs[p & 1];
#pragma unroll
        for (int t = 0; t < 16; t++)
            qa[t] = __builtin_amdgcn_mfma_f32_16x16x32_bf16(a, bfrag(bsu, t, m, quad),
                                                            qa[t], 0, 0, 0);
#pragma unroll
        for (int t = 0; t < 16; t++)
            ka[t] = __builtin_amdgcn_mfma_f32_16x16x32_bf16(a, bfrag(bsu + 16384, t, m, quad),
                                                            ka[t], 0, 0, 0);
        __syncthreads();
    }
#pragma unroll
    for (int t = 0; t < 16; t++) {
        int col = t * 16 + m;
#pragma unroll
        for (int r = 0; r < 4; r++) {
            int row = 16 * wv + quad * 4 + r;
            qa[t][r] += nq[(size_t)sid[row] * 768 + col];
            ka[t][r] += nq[(size_t)did[row] * 768 + 256 + col];
        }
    }
#pragma unroll
    for (int h = 0; h < 4; h++) {
        float p4[4];
#pragma unroll
        for (int r = 0; r < 4; r++) {
            float sum = 0.f;
#pragma unroll
            for (int ss = 0; ss < 4; ss++) {
                int t = h * 4 + ss;
                sum += qa[t][r] * ka[t][r];
            }
            p4[r] = sum;
        }
#pragma unroll
        for (int r = 0; r < 4; r++) {
            p4[r] += __shfl_xor(p4[r], 1, 64);
            p4[r] += __shfl_xor(p4[r], 2, 64);
            p4[r] += __shfl_xor(p4[r], 4, 64);
            p4[r] += __shfl_xor(p4[r], 8, 64);
        }
        if (m == 0) {
#pragma unroll
            for (int r = 0; r < 4; r++)
                scores[(size_t)(e0 + 16 * wv + quad * 4 + r) * 4 + h] = p4[r] * 0.125f;
        }
    }
}

// ---------------- legacy fused edge score kernel (F1 tier, 64 edges) ----------------

__global__ void __launch_bounds__(256) k_qk2(
    const bf16* __restrict__ heG, const int* __restrict__ src, const int* __restrict__ dst,
    const float* __restrict__ nq, const uint4* __restrict__ EQP,
    const uint4* __restrict__ EKP, float* __restrict__ scores) {
    __shared__ uint4 Bs[2][2048];
    __shared__ int sid[64], did[64];
    int tid = threadIdx.x;
    int wv = tid >> 6, lane = tid & 63, quad = lane >> 4, m = lane & 15;
    int e0 = blockIdx.x * 64;
    if (tid < 64) {
        sid[tid] = src[e0 + tid];
        did[tid] = dst[e0 + tid];
    }
#pragma unroll
    for (int i = 0; i < 4; i++) {
        Bs[0][tid + i * 256] = EQP[tid + i * 256];
        Bs[0][1024 + tid + i * 256] = EKP[tid + i * 256];
    }
    __syncthreads();
    int arow = e0 + 16 * wv + m;
    f32x4 qa[16], ka[16];
#pragma unroll
    for (int t = 0; t < 16; t++) {
        qa[t] = (f32x4){0.f, 0.f, 0.f, 0.f};
        ka[t] = (f32x4){0.f, 0.f, 0.f, 0.f};
    }
    for (int p = 0; p < 8; p++) {
        if (p + 1 < 8) {
#pragma unroll
            for (int i = 0; i < 4; i++) {
                Bs[(p + 1) & 1][tid + i * 256] = EQP[(size_t)(p + 1) * 1024 + tid + i * 256];
                Bs[(p + 1) & 1][1024 + tid + i * 256] =
                    EKP[(size_t)(p + 1) * 1024 + tid + i * 256];
            }
        }
        bf16x8 a = *(const bf16x8*)&heG[(size_t)arow * 256 + p * 32 + quad * 8];
        const bf16* bsu = (const bf16*)Bs[p & 1];
#pragma unroll
        for (int t = 0; t < 16; t++)
            qa[t] = __builtin_amdgcn_mfma_f32_16x16x32_bf16(a, bfrag(bsu, t, m, quad),
                                                            qa[t], 0, 0, 0);
#pragma unroll
        for (int t = 0; t < 16; t++)
            ka[t] = __builtin_amdgcn_mfma_f32_16x16x32_bf16(a, bfrag(bsu + 16384, t, m, quad),
                                                            ka[t], 0, 0, 0);
        __syncthreads();
    }
#pragma unroll
    for (int t = 0; t < 16; t++) {
        int col = t * 16 + m;
#pragma unroll
        for (int r = 0; r < 4; r++) {
            int row = 16 * wv + quad * 4 + r;
            qa[t][r] += nq[(size_t)sid[row] * 768 + col];
            ka[t][r] += nq[(size_t)did[row] * 768 + 256 + col];
        }
    }
#pragma unroll
    for (int h = 0; h < 4; h++) {
        float p4[4];
#pragma unroll
        for (int r = 0; r < 4; r++) {
            float sum = 0.f;
#pragma unroll
            for (int ss = 0; ss < 4; ss++) {
                int t = h * 4 + ss;
                sum += qa[t][r] * ka[t][r];
            }
            p4[r] = sum;
        }
#pragma unroll
        for (int r = 0; r < 4; r++) {
            p4[r] += __shfl_xor(p4[r], 1, 64);
            p4[r] += __shfl_xor(p4[r], 2, 64);
            p4[r] += __shfl_xor(p4[r], 4, 64);
            p4[r] += __shfl_xor(p4[r], 8, 64);
        }
        if (m == 0) {
#pragma unroll
            for (int r = 0; r < 4; r++)
                scores[(size_t)(e0 + 16 * wv + quad * 4 + r) * 4 + h] = p4[r] * 0.125f;
        }
    }
}

// ---------------- fused softmax + CSR weighted sums (contiguous segments) ----------------

__global__ void __launch_bounds__(256) k_avfused(
    const int* __restrict__ starts, const int* __restrict__ dstP,
    const float* __restrict__ scores, const bf16* __restrict__ heG,
    const float* __restrict__ nq, bf16* __restrict__ hacc, bf16* __restrict__ avnb) {
    __shared__ float smx[4], sinv[4];
    int n = blockIdx.x, tid = threadIdx.x;
    int h = tid >> 6, lane = tid & 63;
    int s0 = starts[n], s1 = starts[n + 1];
    float mx = -1e30f;
    for (int i = s0 + lane; i < s1; i += 64) mx = fmaxf(mx, scores[(size_t)i * 4 + h]);
    for (int mm = 32; mm >= 1; mm >>= 1) mx = fmaxf(mx, __shfl_xor(mx, mm, 64));
    float den = 0.f;
    for (int i = s0 + lane; i < s1; i += 64) den += __expf(scores[(size_t)i * 4 + h] - mx);
    for (int mm = 32; mm >= 1; mm >>= 1) den += __shfl_xor(den, mm, 64);
    if (lane == 0) {
        smx[h] = mx;
        sinv[h] = 1.0f / den;
    }
    __syncthreads();
    int d = tid;
    float m0 = smx[0], m1 = smx[1], m2 = smx[2], m3 = smx[3];
    float i0 = sinv[0], i1 = sinv[1], i2 = sinv[2], i3 = sinv[3];
    float a0 = 0.f, a1 = 0.f, a2 = 0.f, a3 = 0.f, av = 0.f;
#pragma unroll 2
    for (int i = s0; i < s1; i++) {
        float4 s4 = *(const float4*)&scores[(size_t)i * 4];
        float e0 = __expf(s4.x - m0) * i0;
        float e1 = __expf(s4.y - m1) * i1;
        float e2 = __expf(s4.z - m2) * i2;
        float e3 = __expf(s4.w - m3) * i3;
        float hv = b2f(heG[(size_t)i * 256 + d]);
        a0 += e0 * hv;
        a1 += e1 * hv;
        a2 += e2 * hv;
        a3 += e3 * hv;
        float eh = (h == 0) ? e0 : ((h == 1) ? e1 : ((h == 2) ? e2 : e3));
        av += eh * nq[(size_t)dstP[i] * 768 + 512 + d];
    }
    size_t b = (size_t)n * 1024 + d;
    hacc[b] = f2b(a0);
    hacc[b + 256] = f2b(a1);
    hacc[b + 512] = f2b(a2);
    hacc[b + 768] = f2b(a3);
    avnb[(size_t)n * 256 + d] = f2b(av);
}

// ---------------- dual-A GEMM + residual + layernorm fused (A-direct, B dbuf) ----------
// 128-thread proven version (rounds 8-9, 11)

__global__ void __launch_bounds__(128) k_gnode_ln(
    const bf16* __restrict__ A1, int lda1, const uint4* __restrict__ P1, int ks1,
    const bf16* __restrict__ A2, int lda2, const uint4* __restrict__ P2, int ks2,
    const float* __restrict__ bias, const float* __restrict__ resid,
    const float* __restrict__ g, const float* __restrict__ b,
    float* __restrict__ f32out, bf16* __restrict__ hb) {
    __shared__ uint4 Bs[2][1024];
    int tid = threadIdx.x;
    int wv = tid >> 6, lane = tid & 63, quad = lane >> 4, m = lane & 15;
    int m0 = blockIdx.x * 32;
    int arow = m0 + 16 * wv + m;
    f32x4 acc[16];
#pragma unroll
    for (int t = 0; t < 16; t++) acc[t] = (f32x4){0.f, 0.f, 0.f, 0.f};
#pragma unroll
    for (int i = 0; i < 8; i++) Bs[0][tid + i * 128] = P1[tid + i * 128];
    __syncthreads();
    for (int p = 0; p < ks1; p++) {
        if (p + 1 < ks1) {
#pragma unroll
            for (int i = 0; i < 8; i++)
                Bs[(p + 1) & 1][tid + i * 128] = P1[(size_t)(p + 1) * 1024 + tid + i * 128];
        } else if (ks2 > 0) {
#pragma unroll
            for (int i = 0; i < 8; i++) Bs[(p + 1) & 1][tid + i * 128] = P2[tid + i * 128];
        }
        bf16x8 a = *(const bf16x8*)&A1[(size_t)arow * lda1 + p * 32 + quad * 8];
        const bf16* bsu = (const bf16*)Bs[p & 1];
#pragma unroll
        for (int t = 0; t < 16; t++)
            acc[t] = __builtin_amdgcn_mfma_f32_16x16x32_bf16(a, bfrag(bsu, t, m, quad),
                                                             acc[t], 0, 0, 0);
        __syncthreads();
    }
    for (int q = 0; q < ks2; q++) {
        int pp = ks1 + q;
        if (q + 1 < ks2) {
#pragma unroll
            for (int i = 0; i < 8; i++)
                Bs[(pp + 1) & 1][tid + i * 128] = P2[(size_t)(q + 1) * 1024 + tid + i * 128];
        }
        bf16x8 a = *(const bf16x8*)&A2[(size_t)arow * lda2 + q * 32 + quad * 8];
        const bf16* bsu = (const bf16*)Bs[pp & 1];
#pragma unroll
        for (int t = 0; t < 16; t++)
            acc[t] = __builtin_amdgcn_mfma_f32_16x16x32_bf16(a, bfrag(bsu, t, m, quad),
                                                             acc[t], 0, 0, 0);
        __syncthreads();
    }
#pragma unroll
    for (int r = 0; r < 4; r++) {
        int row = m0 + 16 * wv + quad * 4 + r;
        float s = 0.f;
#pragma unroll
        for (int t = 0; t < 16; t++) {
            int col = t * 16 + m;
            acc[t][r] += bias[col] + resid[(size_t)row * 256 + col];
            s += acc[t][r];
        }
        s += __shfl_xor(s, 1, 64);
        s += __shfl_xor(s, 2, 64);
        s += __shfl_xor(s, 4, 64);
        s += __shfl_xor(s, 8, 64);
        float mu = s * (1.0f / 256.0f);
        float v = 0.f;
#pragma unroll
        for (int t = 0; t < 16; t++) {
            float dd = acc[t][r] - mu;
            v += dd * dd;
        }
        v += __shfl_xor(v, 1, 64);
        v += __shfl_xor(v, 2, 64);
        v += __shfl_xor(v, 4, 64);
        v += __shfl_xor(v, 8, 64);
        float inv = rsqrtf(v * (1.0f / 256.0f) + 1e-5f);
#pragma unroll
        for (int t = 0; t < 16; t++) {
            int col = t * 16 + m;
            float o = (acc[t][r] - mu) * inv * g[col] + b[col];
            f32out[(size_t)row * 256 + col] = o;
            hb[(size_t)row * 256 + col] = f2b(o);
        }
    }
}

// ---------------- tier-1 AV: Ve in-register + atomic scatter (fallback) ----------------

__global__ void __launch_bounds__(256) k_av3(
    const bf16* __restrict__ heG, const int* __restrict__ src, const int* __restrict__ dst,
    const float* __restrict__ nq, const uint4* __restrict__ EVP,
    const float* __restrict__ w, float* __restrict__ attn) {
    __shared__ bf16 As[64][ASPAD];
    __shared__ uint4 Bs[1024];
    __shared__ int sid[64], did[64];
    int tid = threadIdx.x;
    int wv = tid >> 6, lane = tid & 63, quad = lane >> 4, m = lane & 15;
    int e0 = blockIdx.x * 64;
    if (tid < 64) {
        sid[tid] = src[e0 + tid];
        did[tid] = dst[e0 + tid];
    }
    int ar = tid >> 2, kb = (tid & 3) * 8;
    const bf16* bsu = (const bf16*)Bs;
    f32x4 va[16];
#pragma unroll
    for (int t = 0; t < 16; t++) va[t] = (f32x4){0.f, 0.f, 0.f, 0.f};
    for (int p = 0; p < 8; p++) {
        *(uint4*)&As[ar][kb] = *(const uint4*)&heG[(size_t)(e0 + ar) * 256 + p * 32 + kb];
#pragma unroll
        for (int i = 0; i < 4; i++) Bs[tid + i * 256] = EVP[(size_t)p * 1024 + tid + i * 256];
        __syncthreads();
        bf16x8 a = *(const bf16x8*)&As[16 * wv + m][quad * 8];
#pragma unroll
        for (int t = 0; t < 16; t++)
            va[t] = __builtin_amdgcn_mfma_f32_16x16x32_bf16(a, bfrag(bsu, t, m, quad),
                                                            va[t], 0, 0, 0);
        __syncthreads();
    }
    float wrow[4][4];
#pragma unroll
    for (int r = 0; r < 4; r++) {
        int e = e0 + 16 * wv + quad * 4 + r;
#pragma unroll
        for (int h = 0; h < 4; h++) wrow[r][h] = w[(size_t)e * 4 + h];
    }
#pragma unroll
    for (int t = 0; t < 16; t++) {
        int col = t * 16 + m;
        int h = t >> 2;
#pragma unroll
        for (int r = 0; r < 4; r++) {
            int row = 16 * wv + quad * 4 + r;
            float vn = nq[(size_t)did[row] * 768 + 512 + col];
            atomicAdd(&attn[(size_t)sid[row] * 256 + col], wrow[r][h] * (va[t][r] + vn));
        }
    }
}

// ---------------- MFMA QK kernel (fallback tier) ----------------

template <int HE>
__global__ void __launch_bounds__(256) k_qk_mfma(
    const bf16* __restrict__ hnb, const int* __restrict__ src, const int* __restrict__ dst,
    const float* __restrict__ frac, const float* __restrict__ shifts,
    const uint4* __restrict__ WeP, const float* __restrict__ be,
    const bf16* __restrict__ heG,
    const uint4* __restrict__ QP, const uint4* __restrict__ KP,
    const float* __restrict__ bq, const float* __restrict__ bkv,
    float* __restrict__ scores) {
    __shared__ bf16 heb[HE ? 1 : 64][HEPAD];
    __shared__ bf16 As[64][ASPAD];
    __shared__ uint4 Bs[1024];
    __shared__ float dsv[HE ? 1 : 64][3];
    __shared__ int sid[64], did[64];

    int tid = threadIdx.x;
    int wv = tid >> 6, lane = tid & 63, quad = lane >> 4, m = lane & 15;
    int e0 = blockIdx.x * 64;
    if (tid < 64) {
        int e = e0 + tid;
        int sn = src[e], dn = dst[e];
        sid[tid] = sn; did[tid] = dn;
        if constexpr (!HE) {
#pragma unroll
            for (int c = 0; c < 3; c++) {
                float a = frac[dn * 3 + c] - frac[sn * 3 + c] + shifts[e * 3 + c];
                dsv[tid][c] = a - floorf(a);
            }
        }
    }
    __syncthreads();

    int ar = tid >> 2, kb = (tid & 3) * 8;
    const bf16* bsu = (const bf16*)Bs;

    if constexpr (!HE) {
        float d0 = dsv[ar][0], d1 = dsv[ar][1], d2 = dsv[ar][2];
        f32x4 acc1[16];
#pragma unroll
        for (int t = 0; t < 16; t++) acc1[t] = (f32x4){0.f, 0.f, 0.f, 0.f};
        for (int p = 0; p < 19; p++) {
            bf16 t8[8];
#pragma unroll
            for (int j = 0; j < 8; j++) {
                int k = p * 32 + kb + j;
                t8[j] = (k < KF) ? f2b(fval(d0, d1, d2, k)) : (bf16)0;
            }
            *(uint4*)&As[ar][kb] = *(const uint4*)t8;
#pragma unroll
            for (int i = 0; i < 4; i++) Bs[tid + i * 256] = WeP[(size_t)p * 1024 + tid + i * 256];
            __syncthreads();
            bf16x8 a = *(const bf16x8*)&As[16 * wv + m][quad * 8];
#pragma unroll
            for (int t = 0; t < 16; t++)
                acc1[t] = __builtin_amdgcn_mfma_f32_16x16x32_bf16(a, bfrag(bsu, t, m, quad),
                                                                  acc1[t], 0, 0, 0);
            __syncthreads();
        }
#pragma unroll
        for (int t = 0; t < 16; t++) {
            int col = t * 16 + m;
            float bias = be[col];
#pragma unroll
            for (int r = 0; r < 4; r++)
                heb[16 * wv + quad * 4 + r][col] = f2b(acc1[t][r] + bias);
        }
        __syncthreads();
    }

    f32x4 qa[16];
#pragma unroll
    for (int t = 0; t < 16; t++) qa[t] = (f32x4){0.f, 0.f, 0.f, 0.f};
    for (int p = 0; p < 16; p++) {
        if constexpr (HE) {
            const bf16* asrc = (p < 8) ? &hnb[(size_t)sid[ar] * 256 + p * 32 + kb]
                                       : &heG[(size_t)(e0 + ar) * 256 + (p - 8) * 32 + kb];
            *(uint4*)&As[ar][kb] = *(const uint4*)asrc;
        } else {
            if (p < 8)
                *(uint4*)&As[ar][kb] = *(const uint4*)&hnb[(size_t)sid[ar] * 256 + p * 32 + kb];
        }
#pragma unroll
        for (int i = 0; i < 4; i++) Bs[tid + i * 256] = QP[(size_t)p * 1024 + tid + i * 256];
        __syncthreads();
        bf16x8 a;
        if constexpr (HE)
            a = *(const bf16x8*)&As[16 * wv + m][quad * 8];
        else
            a = (p < 8) ? *(const bf16x8*)&As[16 * wv + m][quad * 8]
                        : *(const bf16x8*)&heb[16 * wv + m][(p - 8) * 32 + quad * 8];
#pragma unroll
        for (int t = 0; t < 16; t++)
            qa[t] = __builtin_amdgcn_mfma_f32_16x16x32_bf16(a, bfrag(bsu, t, m, quad),
                                                            qa[t], 0, 0, 0);
        __syncthreads();
    }
    f32x4 ka[16];
#pragma unroll
    for (int t = 0; t < 16; t++) ka[t] = (f32x4){0.f, 0.f, 0.f, 0.f};
    for (int p = 0; p < 16; p++) {
        if constexpr (HE) {
            const bf16* asrc = (p < 8) ? &hnb[(size_t)did[ar] * 256 + p * 32 + kb]
                                       : &heG[(size_t)(e0 + ar) * 256 + (p - 8) * 32 + kb];
            *(uint4*)&As[ar][kb] = *(const uint4*)asrc;
        } else {
            if (p < 8)
                *(uint4*)&As[ar][kb] = *(const uint4*)&hnb[(size_t)did[ar] * 256 + p * 32 + kb];
        }
#pragma unroll
        for (int i = 0; i < 4; i++) Bs[tid + i * 256] = KP[(size_t)p * 1024 + tid + i * 256];
        __syncthreads();
        bf16x8 a;
        if constexpr (HE)
            a = *(const bf16x8*)&As[16 * wv + m][quad * 8];
        else
            a = (p < 8) ? *(const bf16x8*)&As[16 * wv + m][quad * 8]
                        : *(const bf16x8*)&heb[16 * wv + m][(p - 8) * 32 + quad * 8];
#pragma unroll
        for (int t = 0; t < 16; t++)
            ka[t] = __builtin_amdgcn_mfma_f32_16x16x32_bf16(a, bfrag(bsu, t, m, quad),
                                                            ka[t], 0, 0, 0);
        __syncthreads();
    }
#pragma unroll
    for (int h = 0; h < 4; h++) {
        float p4[4];
#pragma unroll
        for (int r = 0; r < 4; r++) {
            float sum = 0.f;
#pragma unroll
            for (int ss = 0; ss < 4; ss++) {
                int t = h * 4 + ss;
                int col = t * 16 + m;
                sum += (qa[t][r] + bq[col]) * (ka[t][r] + bkv[col]);
            }
            p4[r] = sum;
        }
#pragma unroll
        for (int r = 0; r < 4; r++) {
            p4[r] += __shfl_xor(p4[r], 1, 64);
            p4[r] += __shfl_xor(p4[r], 2, 64);
            p4[r] += __shfl_xor(p4[r], 4, 64);
            p4[r] += __shfl_xor(p4[r], 8, 64);
        }
        if (m == 0) {
#pragma unroll
            for (int r = 0; r < 4; r++)
                scores[(size_t)(e0 + 16 * wv + quad * 4 + r) * 4 + h] = p4[r] * 0.125f;
        }
    }
}

// ---------------- MFMA AV kernel (fallback tier) ----------------

template <int HE>
__global__ void __launch_bounds__(256) k_av_mfma(
    const bf16* __restrict__ hnb, const int* __restrict__ src, const int* __restrict__ dst,
    const float* __restrict__ frac, const float* __restrict__ shifts,
    const uint4* __restrict__ WeP, const float* __restrict__ be,
    const bf16* __restrict__ heG,
    const uint4* __restrict__ VP, const float* __restrict__ bkv,
    const float* __restrict__ w, float* __restrict__ attn) {
    __shared__ bf16 heb[HE ? 1 : 64][HEPAD];
    __shared__ bf16 As[64][ASPAD];
    __shared__ uint4 Bs[1024];
    __shared__ float dsv[HE ? 1 : 64][3];
    __shared__ int sid[64], did[64];

    int tid = threadIdx.x;
    int wv = tid >> 6, lane = tid & 63, quad = lane >> 4, m = lane & 15;
    int e0 = blockIdx.x * 64;
    if (tid < 64) {
        int e = e0 + tid;
        int sn = src[e], dn = dst[e];
        sid[tid] = sn; did[tid] = dn;
        if constexpr (!HE) {
#pragma unroll
            for (int c = 0; c < 3; c++) {
                float a = frac[dn * 3 + c] - frac[sn * 3 + c] + shifts[e * 3 + c];
                dsv[tid][c] = a - floorf(a);
            }
        }
    }
    __syncthreads();

    int ar = tid >> 2, kb = (tid & 3) * 8;
    const bf16* bsu = (const bf16*)Bs;

    if constexpr (!HE) {
        float d0 = dsv[ar][0], d1 = dsv[ar][1], d2 = dsv[ar][2];
        f32x4 acc1[16];
#pragma unroll
        for (int t = 0; t < 16; t++) acc1[t] = (f32x4){0.f, 0.f, 0.f, 0.f};
        for (int p = 0; p < 19; p++) {
            bf16 t8[8];
#pragma unroll
            for (int j = 0; j < 8; j++) {
                int k = p * 32 + kb + j;
                t8[j] = (k < KF) ? f2b(fval(d0, d1, d2, k)) : (bf16)0;
            }
            *(uint4*)&As[ar][kb] = *(const uint4*)t8;
#pragma unroll
            for (int i = 0; i < 4; i++) Bs[tid + i * 256] = WeP[(size_t)p * 1024 + tid + i * 256];
            __syncthreads();
            bf16x8 a = *(const bf16x8*)&As[16 * wv + m][quad * 8];
#pragma unroll
            for (int t = 0; t < 16; t++)
                acc1[t] = __builtin_amdgcn_mfma_f32_16x16x32_bf16(a, bfrag(bsu, t, m, quad),
                                                                  acc1[t], 0, 0, 0);
            __syncthreads();
        }
#pragma unroll
        for (int t = 0; t < 16; t++) {
            int col = t * 16 + m;
            float bias = be[col];
#pragma unroll
            for (int r = 0; r < 4; r++)
                heb[16 * wv + quad * 4 + r][col] = f2b(acc1[t][r] + bias);
        }
        __syncthreads();
    }

    f32x4 va[16];
#pragma unroll
    for (int t = 0; t < 16; t++) va[t] = (f32x4){0.f, 0.f, 0.f, 0.f};
    for (int p = 0; p < 16; p++) {
        if constexpr (HE) {
            const bf16* asrc = (p < 8) ? &hnb[(size_t)did[ar] * 256 + p * 32 + kb]
                                       : &heG[(size_t)(e0 + ar) * 256 + (p - 8) * 32 + kb];
            *(uint4*)&As[ar][kb] = *(const uint4*)asrc;
        } else {
            if (p < 8)
                *(uint4*)&As[ar][kb] = *(const uint4*)&hnb[(size_t)did[ar] * 256 + p * 32 + kb];
        }
#pragma unroll
        for (int i = 0; i < 4; i++) Bs[tid + i * 256] = VP[(size_t)p * 1024 + tid + i * 256];
        __syncthreads();
        bf16x8 a;
        if constexpr (HE)
            a = *(const bf16x8*)&As[16 * wv + m][quad * 8];
        else
            a = (p < 8) ? *(const bf16x8*)&As[16 * wv + m][quad * 8]
                        : *(const bf16x8*)&heb[16 * wv + m][(p - 8) * 32 + quad * 8];
#pragma unroll
        for (int t = 0; t < 16; t++)
            va[t] = __builtin_amdgcn_mfma_f32_16x16x32_bf16(a, bfrag(bsu, t, m, quad),
                                                            va[t], 0, 0, 0);
        __syncthreads();
    }
    float wrow[4][4];
#pragma unroll
    for (int r = 0; r < 4; r++) {
        int e = e0 + 16 * wv + quad * 4 + r;
#pragma unroll
        for (int h = 0; h < 4; h++) wrow[r][h] = w[(size_t)e * 4 + h];
    }
#pragma unroll
    for (int t = 0; t < 16; t++) {
        int col = t * 16 + m;
        int h = t >> 2;
        float vb = bkv[256 + col];
#pragma unroll
        for (int r = 0; r < 4; r++) {
            int row = 16 * wv + quad * 4 + r;
            atomicAdd(&attn[(size_t)sid[row] * 256 + col], wrow[r][h] * (va[t][r] + vb));
        }
    }
}

// ---------------- node GEMM via MFMA (A-direct, B double-buffered) ----------------

template <int OUTB>
__global__ void __launch_bounds__(128) k_gnode(
    const bf16* __restrict__ Ab, int lda, const uint4* __restrict__ P, int ksteps,
    const float* __restrict__ bias, int act, float* __restrict__ Cf,
    bf16* __restrict__ Cb, int ldc) {
    __shared__ uint4 Bs[2][1024];
    int tid = threadIdx.x;
    int wv = tid >> 6, lane = tid & 63, quad = lane >> 4, m = lane & 15;
    int m0 = blockIdx.x * 32, g = blockIdx.y;
    const uint4* Pg = P + (size_t)g * ksteps * 1024;
    int arow = m0 + 16 * wv + m;
    f32x4 acc[16];
#pragma unroll
    for (int t = 0; t < 16; t++) acc[t] = (f32x4){0.f, 0.f, 0.f, 0.f};
#pragma unroll
    for (int i = 0; i < 8; i++) Bs[0][tid + i * 128] = Pg[tid + i * 128];
    __syncthreads();
    for (int p = 0; p < ksteps; p++) {
        if (p + 1 < ksteps) {
#pragma unroll
            for (int i = 0; i < 8; i++)
                Bs[(p + 1) & 1][tid + i * 128] = Pg[(size_t)(p + 1) * 1024 + tid + i * 128];
        }
        bf16x8 a = *(const bf16x8*)&Ab[(size_t)arow * lda + p * 32 + quad * 8];
        const bf16* bsu = (const bf16*)Bs[p & 1];
#pragma unroll
        for (int t = 0; t < 16; t++)
            acc[t] = __builtin_amdgcn_mfma_f32_16x16x32_bf16(a, bfrag(bsu, t, m, quad),
                                                             acc[t], 0, 0, 0);
        __syncthreads();
    }
#pragma unroll
    for (int t = 0; t < 16; t++) {
        int col = g * 256 + t * 16 + m;
        float bb = bias ? bias[col] : 0.f;
#pragma unroll
        for (int r = 0; r < 4; r++) {
            int row = m0 + 16 * wv + quad * 4 + r;
            float v = acc[t][r] + bb;
            if (act) v = 0.5f * v * (1.0f + erff(v * 0.7071067811865475f));
            if (OUTB) Cb[(size_t)row * ldc + col] = f2b(v);
            else Cf[(size_t)row * ldc + col] = v;
        }
    }
}

// ---------------- segment softmax (fallback tiers) ----------------

__global__ void k_softmax(const int* __restrict__ starts, const int* __restrict__ eids,
                          float* __restrict__ scores) {
    int n = blockIdx.x;
    int s0 = starts[n], s1 = starts[n + 1];
    int h = threadIdx.x >> 6, lane = threadIdx.x & 63;
    float mx = -1e30f;
    for (int i = s0 + lane; i < s1; i += 64) mx = fmaxf(mx, scores[eids[i] * 4 + h]);
    for (int m = 32; m >= 1; m >>= 1) mx = fmaxf(mx, __shfl_xor(mx, m, 64));
    float den = 0.f;
    for (int i = s0 + lane; i < s1; i += 64) den += __expf(scores[eids[i] * 4 + h] - mx);
    for (int m = 32; m >= 1; m >>= 1) den += __shfl_xor(den, m, 64);
    float inv = 1.0f / den;
    for (int i = s0 + lane; i < s1; i += 64) {
        int e = eids[i];
        scores[e * 4 + h] = __expf(scores[e * 4 + h] - mx) * inv;
    }
}

// ---------------- residual + layernorm (fallback tiers) ----------------

__global__ void k_add_ln(float* __restrict__ h, const float* __restrict__ r,
                         const float* __restrict__ g, const float* __restrict__ b,
                         bf16* __restrict__ hb) {
    __shared__ float red[4];
    int n = blockIdx.x, d = threadIdx.x;
    float x = h[n * DD + d] + r[n * DD + d];
    float v = x;
    for (int m = 32; m >= 1; m >>= 1) v += __shfl_xor(v, m, 64);
    if ((d & 63) == 0) red[d >> 6] = v;
    __syncthreads();
    float mu = (red[0] + red[1] + red[2] + red[3]) * (1.0f / 256.0f);
    __syncthreads();
    float t = x - mu;
    v = t * t;
    for (int m = 32; m >= 1; m >>= 1) v += __shfl_xor(v, m, 64);
    if ((d & 63) == 0) red[d >> 6] = v;
    __syncthreads();
    float var = (red[0] + red[1] + red[2] + red[3]) * (1.0f / 256.0f);
    float out = t * rsqrtf(var + 1e-5f) * g[d] + b[d];
    h[n * DD + d] = out;
    hb[n * DD + d] = f2b(out);
}

__global__ void k_out(const float* __restrict__ h, float* __restrict__ out) {
    int i = blockIdx.x * 256 + threadIdx.x;
    if (i < NN * DD) out[i] = h[i];
}

// ---------------- launch ----------------

extern "C" void kernel_launch(void* const* d_in, const int* in_sizes, int n_in,
                              void* d_out, int out_size, void* d_ws, size_t ws_size,
                              hipStream_t stream) {
    const int* atom_types = (const int*)d_in[0];
    const float* lattices = (const float*)d_in[1];
    const float* frac = (const float*)d_in[2];
    const int* eidx = (const int*)d_in[3];
    const float* shifts = (const float*)d_in[4];
    const int* batch_ids = (const int*)d_in[5];
    const float* atom_emb = (const float*)d_in[6];
    const float* node_W = (const float*)d_in[7];
    const float* node_b = (const float*)d_in[8];
    const float* edge_W = (const float*)d_in[9];
    const float* edge_b = (const float*)d_in[10];
    const float* Wq = (const float*)d_in[11];
    const float* bq = (const float*)d_in[12];
    const float* Wkv = (const float*)d_in[13];
    const float* bkv = (const float*)d_in[14];
    const float* Wo = (const float*)d_in[15];
    const float* bo = (const float*)d_in[16];
    const float* ln1g = (const float*)d_in[17];
    const float* ln1b = (const float*)d_in[18];
    const float* W1 = (const float*)d_in[19];
    const float* b1 = (const float*)d_in[20];
    const float* W2 = (const float*)d_in[21];
    const float* b2w = (const float*)d_in[22];
    const float* ln2g = (const float*)d_in[23];
    const float* ln2b = (const float*)d_in[24];

    char* base = (char*)d_ws;
    size_t off = 0;
    auto alloc = [&](size_t bytes) -> void* {
        void* p = base + off;
        off = (off + bytes + 255) & ~(size_t)255;
        return p;
    };
    int* counts = (int*)alloc((size_t)NN * 4);
    int* cursor = (int*)alloc((size_t)NN * 4);
    int* starts = (int*)alloc((size_t)(NN + 1) * 4);
    int* eids = (int*)alloc((size_t)EE * 4);
    float* lfeat = (float*)alloc((size_t)BB * 6 * 4);
    float* h_n = (float*)alloc((size_t)NN * DD * 4);
    float* attn = (float*)alloc((size_t)NN * DD * 4);
    float* tmp = (float*)alloc((size_t)NN * DD * 4);
    float* scores = tmp;  // first EEP*4 floats; srcP/dstP after (disjoint; total 4.8MB < 8.2MB)
    int* srcP = (int*)(scores + (size_t)EEP * 4);
    int* dstP = srcP + EEP;
    bf16* hnb = (bf16*)alloc((size_t)NN * DD * 2);
    bf16* attnb = (bf16*)alloc((size_t)NN * DD * 2);
    bf16* h1b = (bf16*)alloc((size_t)NN * 1024 * 2);
    bf16* WeP = (bf16*)alloc((size_t)19 * 8192 * 2);
    bf16* QP = (bf16*)alloc((size_t)LL * 16 * 8192 * 2);
    bf16* KP = (bf16*)alloc((size_t)LL * 16 * 8192 * 2);
    bf16* VP = (bf16*)alloc((size_t)LL * 16 * 8192 * 2);
    bf16* WoP = (bf16*)alloc((size_t)LL * 8 * 8192 * 2);
    bf16* W1P = (bf16*)alloc((size_t)LL * 32 * 8192 * 2);
    bf16* W2P = (bf16*)alloc((size_t)LL * 32 * 8192 * 2);
    bf16* heG = (bf16*)alloc((size_t)EEP * DD * 2);  // 102.4 MB (+pad rows)
    size_t off_he = off;
    bf16* NPP = (bf16*)alloc((size_t)LL * 24 * 8192 * 2);  // node panels [l][q|k|v][8]
    bf16* EPP = (bf16*)alloc((size_t)LL * 24 * 8192 * 2);  // edge panels [l][q|k|v][8]
    float* nbias = (float*)alloc((size_t)LL * 768 * 4);
    float* nodeQKV = (float*)alloc((size_t)NN * 768 * 4);  // 24.6 MB
    size_t off_f1 = off;
    bf16* hacc = (bf16*)alloc((size_t)NN * 4 * 256 * 2);    // 16.4 MB
    bf16* VWoP = (bf16*)alloc((size_t)LL * 32 * 8192 * 2);  // 2.1 MB (bdV@Wo panels)
    size_t off_f3 = off;
    const bool useHe = (off_he <= ws_size);
    const bool useF1 = (off_f1 <= ws_size);
    const bool useF3 = (off_f3 <= ws_size);
    bf16* avnb = attnb;           // reuse slot (F3 path only)
    float* VWo_f = (float*)h1b;   // setup-time scratch aliased onto h1b (4.2 MB < 16.4 MB)

    const int* src = eidx;
    const int* dstpub = eidx + EE;

    k_lfeat<<<1, 96, 0, stream>>>(lattices, lfeat);
    k_zero<<<(NN + 255) / 256, 256, 0, stream>>>(counts, NN);
    k_count<<<(EE + 255) / 256, 256, 0, stream>>>(src, counts);
    k_scan<<<1, 256, 0, stream>>>(counts, starts, cursor);
    k_scatter<<<(EE + 255) / 256, 256, 0, stream>>>(src, dstpub, cursor, eids, srcP, dstP);
    if (useF3) k_padinit<<<1, 256, 0, stream>>>(srcP, dstP, heG);
    k_node_init<<<NN, 256, 0, stream>>>(atom_types, batch_ids, atom_emb, node_W, node_b,
                                        lfeat, h_n, hnb);

    k_panel<<<dim3(19, 1, 1), 256, 0, stream>>>(edge_W, 256, 0, 0, 0, KF, WeP, 19, 19);
    k_panel<<<dim3(8, LL, 1), 256, 0, stream>>>(Wo, 256, 0, 0, 256 * 256, 256, WoP, 8, 8);
    k_panel<<<dim3(8, LL, 4), 256, 0, stream>>>(W1, 1024, 0, 0, 256 * 1024, 256, W1P, 8, 32);
    k_panel<<<dim3(32, LL, 1), 256, 0, stream>>>(W2, 256, 0, 0, 1024 * 256, 1024, W2P, 32, 32);

    if (useF1) {
        k_panel<<<dim3(8, LL, 1), 256, 0, stream>>>(Wq, 256, 0, 0, 512 * 256, 256, NPP, 8, 24);
        k_panel<<<dim3(8, LL, 1), 256, 0, stream>>>(Wkv, 512, 0, 0, 512 * 512, 256,
                                                    NPP + 8 * 8192, 8, 24);
        k_panel<<<dim3(8, LL, 1), 256, 0, stream>>>(Wkv, 512, 0, 256, 512 * 512, 256,
                                                    NPP + 16 * 8192, 8, 24);
        k_panel<<<dim3(8, LL, 1), 256, 0, stream>>>(Wq, 256, 256, 0, 512 * 256, 256, EPP, 8, 24);
        k_panel<<<dim3(8, LL, 1), 256, 0, stream>>>(Wkv, 512, 256, 0, 512 * 512, 256,
                                                    EPP + 8 * 8192, 8, 24);
        k_panel<<<dim3(8, LL, 1), 256, 0, stream>>>(Wkv, 512, 256, 256, 512 * 512, 256,
                                                    EPP + 16 * 8192, 8, 24);
        k_catbias<<<LL, 768, 0, stream>>>(bq, bkv, nbias);
        if (useF3) {
            k_vwo<<<dim3(1024, LL), 256, 0, stream>>>(Wkv, Wo, VWo_f);
            k_panel<<<dim3(32, LL, 1), 256, 0, stream>>>(VWo_f, 256, 0, 0, 1024 * 256, 1024,
                                                         VWoP, 32, 32);
        }
    } else {
        k_panel<<<dim3(16, LL, 1), 256, 0, stream>>>(Wq, 256, 0, 0, 512 * 256, 512, QP, 16, 16);
        k_panel<<<dim3(16, LL, 1), 256, 0, stream>>>(Wkv, 512, 0, 0, 512 * 512, 512, KP, 16, 16);
        k_panel<<<dim3(16, LL, 1), 256, 0, stream>>>(Wkv, 512, 0, 256, 512 * 512, 512, VP, 16, 16);
    }

    if (useHe) {
        k_he<<<EE / 64, 256, 0, stream>>>(src, dstpub, useF3 ? eids : nullptr, frac,
                                          shifts, (const uint4*)WeP, edge_b, heG);
    }

    for (int l = 0; l < LL; l++) {
        const uint4* WoPl = (const uint4*)(WoP + (size_t)l * 8 * 8192);
        const uint4* W1Pl = (const uint4*)(W1P + (size_t)l * 32 * 8192);
        const uint4* W2Pl = (const uint4*)(W2P + (size_t)l * 32 * 8192);

        if (useF1 && useF3) {
            const uint4* EQPl = (const uint4*)(EPP + (size_t)l * 24 * 8192);
            const uint4* EKPl = (const uint4*)(EPP + (size_t)l * 24 * 8192 + 8 * 8192);
            const uint4* VWoPl = (const uint4*)(VWoP + (size_t)l * 32 * 8192);
            k_gnode<0><<<dim3(NN / 32, 3), 128, 0, stream>>>(
                hnb, 256, (const uint4*)(NPP + (size_t)l * 24 * 8192), 8,
                nbias + l * 768, 0, nodeQKV, nullptr, 768);
            k_qk3<<<EEP / 128, 512, 0, stream>>>(heG, srcP, dstP, nodeQKV, EQPl, EKPl,
                                                 scores);
            k_avfused<<<NN, 256, 0, stream>>>(starts, dstP, scores, heG, nodeQKV,
                                              hacc, avnb);
            k_gnode_ln<<<NN / 32, 128, 0, stream>>>(
                hacc, 1024, VWoPl, 32, avnb, 256, WoPl, 8,
                bo + l * 256, h_n, ln1g + l * 256, ln1b + l * 256, h_n, hnb);
            k_gnode<1><<<dim3(NN / 32, 4), 128, 0, stream>>>(hnb, 256, W1Pl, 8,
                                                             b1 + l * 1024, 1, nullptr,
                                                             h1b, 1024);
            float* outp = (l == LL - 1) ? (float*)d_out : h_n;
            k_gnode_ln<<<NN / 32, 128, 0, stream>>>(
                h1b, 1024, W2Pl, 32, nullptr, 0, nullptr, 0,
                b2w + l * 256, h_n, ln2g + l * 256, ln2b + l * 256, outp, hnb);
        } else if (useF1) {
            const uint4* EQPl = (const uint4*)(EPP + (size_t)l * 24 * 8192);
            const uint4* EKPl = (const uint4*)(EPP + (size_t)l * 24 * 8192 + 8 * 8192);
            const uint4* EVPl = (const uint4*)(EPP + (size_t)l * 24 * 8192 + 16 * 8192);
            k_gnode<0><<<dim3(NN / 32, 3), 128, 0, stream>>>(
                hnb, 256, (const uint4*)(NPP + (size_t)l * 24 * 8192), 8,
                nbias + l * 768, 0, nodeQKV, nullptr, 768);
            k_qk2<<<EE / 64, 256, 0, stream>>>(heG, src, dstpub, nodeQKV, EQPl, EKPl,
                                               scores);
            k_softmax<<<NN, 256, 0, stream>>>(starts, eids, scores);
            k_zerof<<<(NN * DD + 255) / 256, 256, 0, stream>>>(attn, NN * DD);
            k_av3<<<EE / 64, 256, 0, stream>>>(heG, src, dstpub, nodeQKV, EVPl, scores,
                                               attn);
            k_cvt<<<(NN * DD + 255) / 256, 256, 0, stream>>>(attn, attnb, NN * DD);
            k_gnode<0><<<dim3(NN / 32, 1), 128, 0, stream>>>(attnb, 256, WoPl, 8,
                                                             bo + l * 256, 0, tmp, nullptr,
                                                             256);
            k_add_ln<<<NN, 256, 0, stream>>>(h_n, tmp, ln1g + l * 256, ln1b + l * 256, hnb);
            k_gnode<1><<<dim3(NN / 32, 4), 128, 0, stream>>>(hnb, 256, W1Pl, 8,
                                                             b1 + l * 1024, 1, nullptr,
                                                             h1b, 1024);
            k_gnode<0><<<dim3(NN / 32, 1), 128, 0, stream>>>(h1b, 1024, W2Pl, 32,
                                                             b2w + l * 256, 0, tmp, nullptr,
                                                             256);
            k_add_ln<<<NN, 256, 0, stream>>>(h_n, tmp, ln2g + l * 256, ln2b + l * 256, hnb);
        } else {
            const uint4* QPl = (const uint4*)(QP + (size_t)l * 16 * 8192);
            const uint4* KPl = (const uint4*)(KP + (size_t)l * 16 * 8192);
            const uint4* VPl = (const uint4*)(VP + (size_t)l * 16 * 8192);
            const float* bql = bq + l * 256;
            const float* bkvl = bkv + l * 512;
            if (useHe)
                k_qk_mfma<1><<<EE / 64, 256, 0, stream>>>(hnb, src, dstpub, frac, shifts,
                                                          (const uint4*)WeP, edge_b, heG,
                                                          QPl, KPl, bql, bkvl, scores);
            else
                k_qk_mfma<0><<<EE / 64, 256, 0, stream>>>(hnb, src, dstpub, frac, shifts,
                                                          (const uint4*)WeP, edge_b, nullptr,
                                                          QPl, KPl, bql, bkvl, scores);
            k_softmax<<<NN, 256, 0, stream>>>(starts, eids, scores);
            k_zerof<<<(NN * DD + 255) / 256, 256, 0, stream>>>(attn, NN * DD);
            if (useHe)
                k_av_mfma<1><<<EE / 64, 256, 0, stream>>>(hnb, src, dstpub, frac, shifts,
                                                          (const uint4*)WeP, edge_b, heG,
                                                          VPl, bkvl, scores, attn);
            else
                k_av_mfma<0><<<EE / 64, 256, 0, stream>>>(hnb, src, dstpub, frac, shifts,
                                                          (const uint4*)WeP, edge_b, nullptr,
                                                          VPl, bkvl, scores, attn);
            k_cvt<<<(NN * DD + 255) / 256, 256, 0, stream>>>(attn, attnb, NN * DD);
            k_gnode<0><<<dim3(NN / 32, 1), 128, 0, stream>>>(attnb, 256, WoPl, 8,
                                                             bo + l * 256, 0, tmp, nullptr,
                                                             256);
            k_add_ln<<<NN, 256, 0, stream>>>(h_n, tmp, ln1g + l * 256, ln1b + l * 256, hnb);
            k_gnode<1><<<dim3(NN / 32, 4), 128, 0, stream>>>(hnb, 256, W1Pl, 8,
                                                             b1 + l * 1024, 1, nullptr,
                                                             h1b, 1024);
            k_gnode<0><<<dim3(NN / 32, 1), 128, 0, stream>>>(h1b, 1024, W2Pl, 32,
                                                             b2w + l * 256, 0, tmp, nullptr,
                                                             256);
            k_add_ln<<<NN, 256, 0, stream>>>(h_n, tmp, ln2g + l * 256, ln2b + l * 256, hnb);
        }
    }
    if (!(useF1 && useF3))
        k_out<<<(NN * DD + 255) / 256, 256, 0, stream>>>(h_n, (float*)d_out);
}

// Round 14
// 1880.625 us; speedup vs baseline: 1.0618x; 1.0618x over previous
//
#include <hip/hip_runtime.h>

#define NN 8000
#define EE 200000
#define EEP 200064
#define BB 16
#define DD 256
#define LL 4
#define KF 600
#define HEPAD 280
#define ASPAD 40

typedef unsigned short bf16;
typedef short bf16x8 __attribute__((ext_vector_type(8)));
typedef float f32x4 __attribute__((ext_vector_type(4)));

__device__ __forceinline__ float b2f(bf16 u) { return __uint_as_float(((unsigned)u) << 16); }
__device__ __forceinline__ bf16 f2b(float f) {
    unsigned u = __float_as_uint(f);
    u = u + 0x7fffu + ((u >> 16) & 1u);
    return (bf16)(u >> 16);
}

// sin/cos of 2*pi*d*f via v_sin/v_cos in revolutions: sin(2pi*t), t = fract(d*f)
__device__ __forceinline__ float fvalr(float d0, float d1, float d2, int j) {
    int jj = (j < 300) ? j : j - 300;
    int c = jj / 100;
    int f = jj - c * 100;
    float d = (c == 0) ? d0 : ((c == 1) ? d1 : d2);
    float t = d * (float)f;
    t = t - floorf(t);
    return (j < 300) ? __builtin_amdgcn_sinf(t) : __builtin_amdgcn_cosf(t);
}

// legacy radians version (fallback kernels)
__device__ __forceinline__ float fval(float d0, float d1, float d2, int j) {
    int jj = (j < 300) ? j : j - 300;
    int c = jj / 100;
    int f = jj - c * 100;
    float d = (c == 0) ? d0 : ((c == 1) ? d1 : d2);
    float ang = 6.283185307179586f * d * (float)f;
    return (j < 300) ? __sinf(ang) : __cosf(ang);
}

// b-fragment read from a swizzled 256x32 panel in LDS: n = t*16+m, kblk swizzled
__device__ __forceinline__ bf16x8 bfrag(const bf16* bsu, int t, int m, int quad) {
    int q2 = (quad + ((m >> 1) & 3)) & 3;
    return *(const bf16x8*)&bsu[(t * 16 + m) * 32 + q2 * 8];
}

// ---------------- setup ----------------

__global__ void k_lfeat(const float* __restrict__ lat, float* __restrict__ lf) {
    int t = threadIdx.x;
    if (t >= BB * 6) return;
    int b = t / 6, p = t % 6;
    const int rr[6] = {0, 0, 0, 1, 1, 2};
    const int cc[6] = {0, 1, 2, 1, 2, 2};
    float acc = 0.f;
    for (int i = 0; i < 3; i++)
        acc += lat[b * 9 + i * 3 + rr[p]] * lat[b * 9 + i * 3 + cc[p]];
    lf[b * 6 + p] = acc;
}

__global__ void k_zero(int* __restrict__ p, int n) {
    int i = blockIdx.x * 256 + threadIdx.x;
    if (i < n) p[i] = 0;
}

__global__ void k_zerof(float* __restrict__ p, int n) {
    int i = blockIdx.x * 256 + threadIdx.x;
    if (i < n) p[i] = 0.f;
}

__global__ void k_count(const int* __restrict__ src, int* __restrict__ counts) {
    int e = blockIdx.x * 256 + threadIdx.x;
    if (e < EE) atomicAdd(&counts[src[e]], 1);
}

__global__ void k_scan(const int* __restrict__ counts, int* __restrict__ starts,
                       int* __restrict__ cursor) {
    __shared__ int ssum[256];
    int tid = threadIdx.x;
    int base = tid * 32;
    int local = 0;
    for (int i = 0; i < 32; i++) {
        int r = base + i;
        if (r < NN) local += counts[r];
    }
    ssum[tid] = local;
    __syncthreads();
    for (int off = 1; off < 256; off <<= 1) {
        int v = (tid >= off) ? ssum[tid - off] : 0;
        __syncthreads();
        ssum[tid] += v;
        __syncthreads();
    }
    int run = (tid == 0) ? 0 : ssum[tid - 1];
    for (int i = 0; i < 32; i++) {
        int r = base + i;
        if (r < NN) {
            starts[r] = run;
            cursor[r] = run;
            run += counts[r];
        }
    }
    if (tid == 255) starts[NN] = ssum[255];
}

// scatter also emits CSR-permuted src/dst arrays
__global__ void k_scatter(const int* __restrict__ src, const int* __restrict__ dst,
                          int* __restrict__ cursor, int* __restrict__ eids,
                          int* __restrict__ srcP, int* __restrict__ dstP) {
    int e = blockIdx.x * 256 + threadIdx.x;
    if (e >= EE) return;
    int s = src[e];
    int pos = atomicAdd(&cursor[s], 1);
    eids[pos] = e;
    srcP[pos] = s;
    dstP[pos] = dst[e];
}

// init pad entries [EE, EEP): srcP/dstP = 0, heG pad rows = 0
__global__ void k_padinit(int* __restrict__ srcP, int* __restrict__ dstP,
                          bf16* __restrict__ heG) {
    int t = threadIdx.x;
    if (t < EEP - EE) {
        srcP[EE + t] = 0;
        dstP[EE + t] = 0;
    }
    for (int i = t; i < (EEP - EE) * 256; i += 256) heG[(size_t)EE * 256 + i] = 0;
}

__global__ void k_node_init(const int* __restrict__ at, const int* __restrict__ bid,
                            const float* __restrict__ emb, const float* __restrict__ W,
                            const float* __restrict__ nb, const float* __restrict__ lf,
                            float* __restrict__ hn, bf16* __restrict__ hb) {
    __shared__ float arow[262];
    int n = blockIdx.x, d = threadIdx.x;
    arow[d] = emb[at[n] * DD + d];
    if (d < 6) arow[256 + d] = lf[bid[n] * 6 + d];
    __syncthreads();
    float acc = nb[d];
    for (int k = 0; k < 262; k++) acc += arow[k] * W[k * DD + d];
    hn[n * DD + d] = acc;
    hb[n * DD + d] = f2b(acc);
}

__global__ void k_cvt(const float* __restrict__ src, bf16* __restrict__ dst, int n) {
    int i = blockIdx.x * 256 + threadIdx.x;
    if (i < n) dst[i] = f2b(src[i]);
}

// cat bias per layer: out[l][0:256]=bq, [256:768]=bkv
__global__ void k_catbias(const float* __restrict__ bq, const float* __restrict__ bkv,
                          float* __restrict__ out) {
    int l = blockIdx.x, t = threadIdx.x;
    out[l * 768 + t] = (t < 256) ? bq[l * 256 + t] : bkv[l * 512 + (t - 256)];
}

// ---------------- swizzled panel builder ----------------

__global__ void k_panel(const float* __restrict__ W, int ldw, int r0, int c0,
                        size_t wlstride, int Ktot, bf16* __restrict__ dst,
                        int pcount, int lstride) {
    int p = blockIdx.x, l = blockIdx.y, g = blockIdx.z, n = threadIdx.x;
    const float* Wl = W + (size_t)l * wlstride;
    bf16* d = dst + ((size_t)l * lstride + (size_t)g * pcount + p) * 8192;
    int c = c0 + g * 256 + n;
    for (int kk = 0; kk < 32; kk++) {
        int kl = p * 32 + kk;
        float v = (kl < Ktot) ? Wl[(size_t)(r0 + kl) * ldw + c] : 0.f;
        int swz = ((((kk >> 3) + ((n >> 1) & 3)) & 3)) * 8 + (kk & 7);
        d[n * 32 + swz] = f2b(v);
    }
}

// VWo[l][r][c] = sum_n Wv_lo[k][h*64+n] * Wo[h*64+n][c], r = h*256+k
__global__ void k_vwo(const float* __restrict__ Wkv, const float* __restrict__ Wo,
                      float* __restrict__ out) {
    int r = blockIdx.x, l = blockIdx.y, c = threadIdx.x;
    int h = r >> 8, k = r & 255;
    const float* wv = Wkv + (size_t)l * 512 * 512 + (size_t)(256 + k) * 512 + 256 + h * 64;
    const float* wo = Wo + (size_t)l * 256 * 256 + (size_t)(h * 64) * 256 + c;
    float acc = 0.f;
    for (int n = 0; n < 64; n++) acc += wv[n] * wo[(size_t)n * 256];
    out[((size_t)l * 1024 + r) * 256 + c] = acc;
}

// ---------------- he precompute (per-lane fvals, B double-buffered, 1 barrier/p) ----------
// round-8-proven form: separate heb + Bs[2]

__global__ void __launch_bounds__(256) k_he(
    const int* __restrict__ src, const int* __restrict__ dst,
    const int* __restrict__ eids,
    const float* __restrict__ frac, const float* __restrict__ shifts,
    const uint4* __restrict__ WeP, const float* __restrict__ be,
    bf16* __restrict__ heG) {
    __shared__ bf16 heb[64][HEPAD];
    __shared__ uint4 Bs[2][1024];
    __shared__ float dsv[64][3];

    int tid = threadIdx.x;
    int wv = tid >> 6, lane = tid & 63, quad = lane >> 4, m = lane & 15;
    int e0 = blockIdx.x * 64;
    if (tid < 64) {
        int e = eids ? eids[e0 + tid] : (e0 + tid);
        int sn = src[e], dn = dst[e];
#pragma unroll
        for (int c = 0; c < 3; c++) {
            float a = frac[dn * 3 + c] - frac[sn * 3 + c] + shifts[e * 3 + c];
            dsv[tid][c] = a - floorf(a);
        }
    }
#pragma unroll
    for (int i = 0; i < 4; i++) Bs[0][tid + i * 256] = WeP[tid + i * 256];
    __syncthreads();

    int row = 16 * wv + m;
    float d0 = dsv[row][0], d1 = dsv[row][1], d2 = dsv[row][2];

    f32x4 acc1[16];
#pragma unroll
    for (int t = 0; t < 16; t++) acc1[t] = (f32x4){0.f, 0.f, 0.f, 0.f};
    for (int p = 0; p < 19; p++) {
        if (p + 1 < 19) {
#pragma unroll
            for (int i = 0; i < 4; i++)
                Bs[(p + 1) & 1][tid + i * 256] = WeP[(size_t)(p + 1) * 1024 + tid + i * 256];
        }
        bf16 t8[8];
#pragma unroll
        for (int j = 0; j < 8; j++) {
            int k = p * 32 + quad * 8 + j;
            t8[j] = (k < KF) ? f2b(fvalr(d0, d1, d2, k)) : (bf16)0;
        }
        bf16x8 a = *(const bf16x8*)t8;
        const bf16* bsu = (const bf16*)Bs[p & 1];
#pragma unroll
        for (int t = 0; t < 16; t++)
            acc1[t] = __builtin_amdgcn_mfma_f32_16x16x32_bf16(a, bfrag(bsu, t, m, quad),
                                                              acc1[t], 0, 0, 0);
        __syncthreads();
    }
#pragma unroll
    for (int t = 0; t < 16; t++) {
        int col = t * 16 + m;
        float bias = be[col];
#pragma unroll
        for (int r = 0; r < 4; r++)
            heb[16 * wv + quad * 4 + r][col] = f2b(acc1[t][r] + bias);
    }
    __syncthreads();
#pragma unroll
    for (int i = 0; i < 8; i++) {
        int idx = tid * 8 + i;
        int rw = idx >> 5, c = idx & 31;
        *(uint4*)&heG[(size_t)(e0 + rw) * 256 + c * 8] = *(const uint4*)&heb[rw][c * 8];
    }
}

// ---------------- fused edge score kernel: 512 threads, 128 edges, A-prefetch ----------
// (ONLY change this round: 1-deep register prefetch of the A fragment)

__global__ void __launch_bounds__(512) k_qk3(
    const bf16* __restrict__ heG, const int* __restrict__ src, const int* __restrict__ dst,
    const float* __restrict__ nq, const uint4* __restrict__ EQP,
    const uint4* __restrict__ EKP, float* __restrict__ scores) {
    __shared__ uint4 Bs[2][2048];  // per buffer: Q panel [0,1024) + K panel [1024,2048)
    __shared__ int sid[128], did[128];
    int tid = threadIdx.x;
    int wv = tid >> 6, lane = tid & 63, quad = lane >> 4, m = lane & 15;
    int e0 = blockIdx.x * 128;
    if (tid < 128) {
        sid[tid] = src[e0 + tid];
        did[tid] = dst[e0 + tid];
    }
#pragma unroll
    for (int i = 0; i < 2; i++) {
        Bs[0][tid + i * 512] = EQP[tid + i * 512];
        Bs[0][1024 + tid + i * 512] = EKP[tid + i * 512];
    }
    __syncthreads();
    int arow = e0 + 16 * wv + m;
    const bf16* abase = &heG[(size_t)arow * 256 + quad * 8];
    f32x4 qa[16], ka[16];
#pragma unroll
    for (int t = 0; t < 16; t++) {
        qa[t] = (f32x4){0.f, 0.f, 0.f, 0.f};
        ka[t] = (f32x4){0.f, 0.f, 0.f, 0.f};
    }
    bf16x8 a = *(const bf16x8*)abase;
    for (int p = 0; p < 8; p++) {
        bf16x8 anext = (p + 1 < 8) ? *(const bf16x8*)(abase + (p + 1) * 32) : a;
        if (p + 1 < 8) {
#pragma unroll
            for (int i = 0; i < 2; i++) {
                Bs[(p + 1) & 1][tid + i * 512] = EQP[(size_t)(p + 1) * 1024 + tid + i * 512];
                Bs[(p + 1) & 1][1024 + tid + i * 512] =
                    EKP[(size_t)(p + 1) * 1024 + tid + i * 512];
            }
        }
        const bf16* bsu = (const bf16*)Bs[p & 1];
#pragma unroll
        for (int t = 0; t < 16; t++)
            qa[t] = __builtin_amdgcn_mfma_f32_16x16x32_bf16(a, bfrag(bsu, t, m, quad),
                                                            qa[t], 0, 0, 0);
#pragma unroll
        for (int t = 0; t < 16; t++)
            ka[t] = __builtin_amdgcn_mfma_f32_16x16x32_bf16(a, bfrag(bsu + 16384, t, m, quad),
                                                            ka[t], 0, 0, 0);
        __syncthreads();
        a = anext;
    }
#pragma unroll
    for (int t = 0; t < 16; t++) {
        int col = t * 16 + m;
#pragma unroll
        for (int r = 0; r < 4; r++) {
            int row = 16 * wv + quad * 4 + r;
            qa[t][r] += nq[(size_t)sid[row] * 768 + col];
            ka[t][r] += nq[(size_t)did[row] * 768 + 256 + col];
        }
    }
#pragma unroll
    for (int h = 0; h < 4; h++) {
        float p4[4];
#pragma unroll
        for (int r = 0; r < 4; r++) {
            float sum = 0.f;
#pragma unroll
            for (int ss = 0; ss < 4; ss++) {
                int t = h * 4 + ss;
                sum += qa[t][r] * ka[t][r];
            }
            p4[r] = sum;
        }
#pragma unroll
        for (int r = 0; r < 4; r++) {
            p4[r] += __shfl_xor(p4[r], 1, 64);
            p4[r] += __shfl_xor(p4[r], 2, 64);
            p4[r] += __shfl_xor(p4[r], 4, 64);
            p4[r] += __shfl_xor(p4[r], 8, 64);
        }
        if (m == 0) {
#pragma unroll
            for (int r = 0; r < 4; r++)
                scores[(size_t)(e0 + 16 * wv + quad * 4 + r) * 4 + h] = p4[r] * 0.125f;
        }
    }
}

// ---------------- legacy fused edge score kernel (F1 tier, 64 edges) ----------------

__global__ void __launch_bounds__(256) k_qk2(
    const bf16* __restrict__ heG, const int* __restrict__ src, const int* __restrict__ dst,
    const float* __restrict__ nq, const uint4* __restrict__ EQP,
    const uint4* __restrict__ EKP, float* __restrict__ scores) {
    __shared__ uint4 Bs[2][2048];
    __shared__ int sid[64], did[64];
    int tid = threadIdx.x;
    int wv = tid >> 6, lane = tid & 63, quad = lane >> 4, m = lane & 15;
    int e0 = blockIdx.x * 64;
    if (tid < 64) {
        sid[tid] = src[e0 + tid];
        did[tid] = dst[e0 + tid];
    }
#pragma unroll
    for (int i = 0; i < 4; i++) {
        Bs[0][tid + i * 256] = EQP[tid + i * 256];
        Bs[0][1024 + tid + i * 256] = EKP[tid + i * 256];
    }
    __syncthreads();
    int arow = e0 + 16 * wv + m;
    f32x4 qa[16], ka[16];
#pragma unroll
    for (int t = 0; t < 16; t++) {
        qa[t] = (f32x4){0.f, 0.f, 0.f, 0.f};
        ka[t] = (f32x4){0.f, 0.f, 0.f, 0.f};
    }
    for (int p = 0; p < 8; p++) {
        if (p + 1 < 8) {
#pragma unroll
            for (int i = 0; i < 4; i++) {
                Bs[(p + 1) & 1][tid + i * 256] = EQP[(size_t)(p + 1) * 1024 + tid + i * 256];
                Bs[(p + 1) & 1][1024 + tid + i * 256] =
                    EKP[(size_t)(p + 1) * 1024 + tid + i * 256];
            }
        }
        bf16x8 a = *(const bf16x8*)&heG[(size_t)arow * 256 + p * 32 + quad * 8];
        const bf16* bsu = (const bf16*)Bs[p & 1];
#pragma unroll
        for (int t = 0; t < 16; t++)
            qa[t] = __builtin_amdgcn_mfma_f32_16x16x32_bf16(a, bfrag(bsu, t, m, quad),
                                                            qa[t], 0, 0, 0);
#pragma unroll
        for (int t = 0; t < 16; t++)
            ka[t] = __builtin_amdgcn_mfma_f32_16x16x32_bf16(a, bfrag(bsu + 16384, t, m, quad),
                                                            ka[t], 0, 0, 0);
        __syncthreads();
    }
#pragma unroll
    for (int t = 0; t < 16; t++) {
        int col = t * 16 + m;
#pragma unroll
        for (int r = 0; r < 4; r++) {
            int row = 16 * wv + quad * 4 + r;
            qa[t][r] += nq[(size_t)sid[row] * 768 + col];
            ka[t][r] += nq[(size_t)did[row] * 768 + 256 + col];
        }
    }
#pragma unroll
    for (int h = 0; h < 4; h++) {
        float p4[4];
#pragma unroll
        for (int r = 0; r < 4; r++) {
            float sum = 0.f;
#pragma unroll
            for (int ss = 0; ss < 4; ss++) {
                int t = h * 4 + ss;
                sum += qa[t][r] * ka[t][r];
            }
            p4[r] = sum;
        }
#pragma unroll
        for (int r = 0; r < 4; r++) {
            p4[r] += __shfl_xor(p4[r], 1, 64);
            p4[r] += __shfl_xor(p4[r], 2, 64);
            p4[r] += __shfl_xor(p4[r], 4, 64);
            p4[r] += __shfl_xor(p4[r], 8, 64);
        }
        if (m == 0) {
#pragma unroll
            for (int r = 0; r < 4; r++)
                scores[(size_t)(e0 + 16 * wv + quad * 4 + r) * 4 + h] = p4[r] * 0.125f;
        }
    }
}

// ---------------- fused softmax + CSR weighted sums (contiguous segments) ----------------

__global__ void __launch_bounds__(256) k_avfused(
    const int* __restrict__ starts, const int* __restrict__ dstP,
    const float* __restrict__ scores, const bf16* __restrict__ heG,
    const float* __restrict__ nq, bf16* __restrict__ hacc, bf16* __restrict__ avnb) {
    __shared__ float smx[4], sinv[4];
    int n = blockIdx.x, tid = threadIdx.x;
    int h = tid >> 6, lane = tid & 63;
    int s0 = starts[n], s1 = starts[n + 1];
    float mx = -1e30f;
    for (int i = s0 + lane; i < s1; i += 64) mx = fmaxf(mx, scores[(size_t)i * 4 + h]);
    for (int mm = 32; mm >= 1; mm >>= 1) mx = fmaxf(mx, __shfl_xor(mx, mm, 64));
    float den = 0.f;
    for (int i = s0 + lane; i < s1; i += 64) den += __expf(scores[(size_t)i * 4 + h] - mx);
    for (int mm = 32; mm >= 1; mm >>= 1) den += __shfl_xor(den, mm, 64);
    if (lane == 0) {
        smx[h] = mx;
        sinv[h] = 1.0f / den;
    }
    __syncthreads();
    int d = tid;
    float m0 = smx[0], m1 = smx[1], m2 = smx[2], m3 = smx[3];
    float i0 = sinv[0], i1 = sinv[1], i2 = sinv[2], i3 = sinv[3];
    float a0 = 0.f, a1 = 0.f, a2 = 0.f, a3 = 0.f, av = 0.f;
#pragma unroll 2
    for (int i = s0; i < s1; i++) {
        float4 s4 = *(const float4*)&scores[(size_t)i * 4];
        float e0 = __expf(s4.x - m0) * i0;
        float e1 = __expf(s4.y - m1) * i1;
        float e2 = __expf(s4.z - m2) * i2;
        float e3 = __expf(s4.w - m3) * i3;
        float hv = b2f(heG[(size_t)i * 256 + d]);
        a0 += e0 * hv;
        a1 += e1 * hv;
        a2 += e2 * hv;
        a3 += e3 * hv;
        float eh = (h == 0) ? e0 : ((h == 1) ? e1 : ((h == 2) ? e2 : e3));
        av += eh * nq[(size_t)dstP[i] * 768 + 512 + d];
    }
    size_t b = (size_t)n * 1024 + d;
    hacc[b] = f2b(a0);
    hacc[b + 256] = f2b(a1);
    hacc[b + 512] = f2b(a2);
    hacc[b + 768] = f2b(a3);
    avnb[(size_t)n * 256 + d] = f2b(av);
}

// ---------------- dual-A GEMM + residual + layernorm fused (A-direct, B dbuf) ----------
// 128-thread proven version (rounds 8-9, 11, 13)

__global__ void __launch_bounds__(128) k_gnode_ln(
    const bf16* __restrict__ A1, int lda1, const uint4* __restrict__ P1, int ks1,
    const bf16* __restrict__ A2, int lda2, const uint4* __restrict__ P2, int ks2,
    const float* __restrict__ bias, const float* __restrict__ resid,
    const float* __restrict__ g, const float* __restrict__ b,
    float* __restrict__ f32out, bf16* __restrict__ hb) {
    __shared__ uint4 Bs[2][1024];
    int tid = threadIdx.x;
    int wv = tid >> 6, lane = tid & 63, quad = lane >> 4, m = lane & 15;
    int m0 = blockIdx.x * 32;
    int arow = m0 + 16 * wv + m;
    f32x4 acc[16];
#pragma unroll
    for (int t = 0; t < 16; t++) acc[t] = (f32x4){0.f, 0.f, 0.f, 0.f};
#pragma unroll
    for (int i = 0; i < 8; i++) Bs[0][tid + i * 128] = P1[tid + i * 128];
    __syncthreads();
    for (int p = 0; p < ks1; p++) {
        if (p + 1 < ks1) {
#pragma unroll
            for (int i = 0; i < 8; i++)
                Bs[(p + 1) & 1][tid + i * 128] = P1[(size_t)(p + 1) * 1024 + tid + i * 128];
        } else if (ks2 > 0) {
#pragma unroll
            for (int i = 0; i < 8; i++) Bs[(p + 1) & 1][tid + i * 128] = P2[tid + i * 128];
        }
        bf16x8 a = *(const bf16x8*)&A1[(size_t)arow * lda1 + p * 32 + quad * 8];
        const bf16* bsu = (const bf16*)Bs[p & 1];
#pragma unroll
        for (int t = 0; t < 16; t++)
            acc[t] = __builtin_amdgcn_mfma_f32_16x16x32_bf16(a, bfrag(bsu, t, m, quad),
                                                             acc[t], 0, 0, 0);
        __syncthreads();
    }
    for (int q = 0; q < ks2; q++) {
        int pp = ks1 + q;
        if (q + 1 < ks2) {
#pragma unroll
            for (int i = 0; i < 8; i++)
                Bs[(pp + 1) & 1][tid + i * 128] = P2[(size_t)(q + 1) * 1024 + tid + i * 128];
        }
        bf16x8 a = *(const bf16x8*)&A2[(size_t)arow * lda2 + q * 32 + quad * 8];
        const bf16* bsu = (const bf16*)Bs[pp & 1];
#pragma unroll
        for (int t = 0; t < 16; t++)
            acc[t] = __builtin_amdgcn_mfma_f32_16x16x32_bf16(a, bfrag(bsu, t, m, quad),
                                                             acc[t], 0, 0, 0);
        __syncthreads();
    }
#pragma unroll
    for (int r = 0; r < 4; r++) {
        int row = m0 + 16 * wv + quad * 4 + r;
        float s = 0.f;
#pragma unroll
        for (int t = 0; t < 16; t++) {
            int col = t * 16 + m;
            acc[t][r] += bias[col] + resid[(size_t)row * 256 + col];
            s += acc[t][r];
        }
        s += __shfl_xor(s, 1, 64);
        s += __shfl_xor(s, 2, 64);
        s += __shfl_xor(s, 4, 64);
        s += __shfl_xor(s, 8, 64);
        float mu = s * (1.0f / 256.0f);
        float v = 0.f;
#pragma unroll
        for (int t = 0; t < 16; t++) {
            float dd = acc[t][r] - mu;
            v += dd * dd;
        }
        v += __shfl_xor(v, 1, 64);
        v += __shfl_xor(v, 2, 64);
        v += __shfl_xor(v, 4, 64);
        v += __shfl_xor(v, 8, 64);
        float inv = rsqrtf(v * (1.0f / 256.0f) + 1e-5f);
#pragma unroll
        for (int t = 0; t < 16; t++) {
            int col = t * 16 + m;
            float o = (acc[t][r] - mu) * inv * g[col] + b[col];
            f32out[(size_t)row * 256 + col] = o;
            hb[(size_t)row * 256 + col] = f2b(o);
        }
    }
}

// ---------------- tier-1 AV: Ve in-register + atomic scatter (fallback) ----------------

__global__ void __launch_bounds__(256) k_av3(
    const bf16* __restrict__ heG, const int* __restrict__ src, const int* __restrict__ dst,
    const float* __restrict__ nq, const uint4* __restrict__ EVP,
    const float* __restrict__ w, float* __restrict__ attn) {
    __shared__ bf16 As[64][ASPAD];
    __shared__ uint4 Bs[1024];
    __shared__ int sid[64], did[64];
    int tid = threadIdx.x;
    int wv = tid >> 6, lane = tid & 63, quad = lane >> 4, m = lane & 15;
    int e0 = blockIdx.x * 64;
    if (tid < 64) {
        sid[tid] = src[e0 + tid];
        did[tid] = dst[e0 + tid];
    }
    int ar = tid >> 2, kb = (tid & 3) * 8;
    const bf16* bsu = (const bf16*)Bs;
    f32x4 va[16];
#pragma unroll
    for (int t = 0; t < 16; t++) va[t] = (f32x4){0.f, 0.f, 0.f, 0.f};
    for (int p = 0; p < 8; p++) {
        *(uint4*)&As[ar][kb] = *(const uint4*)&heG[(size_t)(e0 + ar) * 256 + p * 32 + kb];
#pragma unroll
        for (int i = 0; i < 4; i++) Bs[tid + i * 256] = EVP[(size_t)p * 1024 + tid + i * 256];
        __syncthreads();
        bf16x8 a = *(const bf16x8*)&As[16 * wv + m][quad * 8];
#pragma unroll
        for (int t = 0; t < 16; t++)
            va[t] = __builtin_amdgcn_mfma_f32_16x16x32_bf16(a, bfrag(bsu, t, m, quad),
                                                            va[t], 0, 0, 0);
        __syncthreads();
    }
    float wrow[4][4];
#pragma unroll
    for (int r = 0; r < 4; r++) {
        int e = e0 + 16 * wv + quad * 4 + r;
#pragma unroll
        for (int h = 0; h < 4; h++) wrow[r][h] = w[(size_t)e * 4 + h];
    }
#pragma unroll
    for (int t = 0; t < 16; t++) {
        int col = t * 16 + m;
        int h = t >> 2;
#pragma unroll
        for (int r = 0; r < 4; r++) {
            int row = 16 * wv + quad * 4 + r;
            float vn = nq[(size_t)did[row] * 768 + 512 + col];
            atomicAdd(&attn[(size_t)sid[row] * 256 + col], wrow[r][h] * (va[t][r] + vn));
        }
    }
}

// ---------------- MFMA QK kernel (fallback tier) ----------------

template <int HE>
__global__ void __launch_bounds__(256) k_qk_mfma(
    const bf16* __restrict__ hnb, const int* __restrict__ src, const int* __restrict__ dst,
    const float* __restrict__ frac, const float* __restrict__ shifts,
    const uint4* __restrict__ WeP, const float* __restrict__ be,
    const bf16* __restrict__ heG,
    const uint4* __restrict__ QP, const uint4* __restrict__ KP,
    const float* __restrict__ bq, const float* __restrict__ bkv,
    float* __restrict__ scores) {
    __shared__ bf16 heb[HE ? 1 : 64][HEPAD];
    __shared__ bf16 As[64][ASPAD];
    __shared__ uint4 Bs[1024];
    __shared__ float dsv[HE ? 1 : 64][3];
    __shared__ int sid[64], did[64];

    int tid = threadIdx.x;
    int wv = tid >> 6, lane = tid & 63, quad = lane >> 4, m = lane & 15;
    int e0 = blockIdx.x * 64;
    if (tid < 64) {
        int e = e0 + tid;
        int sn = src[e], dn = dst[e];
        sid[tid] = sn; did[tid] = dn;
        if constexpr (!HE) {
#pragma unroll
            for (int c = 0; c < 3; c++) {
                float a = frac[dn * 3 + c] - frac[sn * 3 + c] + shifts[e * 3 + c];
                dsv[tid][c] = a - floorf(a);
            }
        }
    }
    __syncthreads();

    int ar = tid >> 2, kb = (tid & 3) * 8;
    const bf16* bsu = (const bf16*)Bs;

    if constexpr (!HE) {
        float d0 = dsv[ar][0], d1 = dsv[ar][1], d2 = dsv[ar][2];
        f32x4 acc1[16];
#pragma unroll
        for (int t = 0; t < 16; t++) acc1[t] = (f32x4){0.f, 0.f, 0.f, 0.f};
        for (int p = 0; p < 19; p++) {
            bf16 t8[8];
#pragma unroll
            for (int j = 0; j < 8; j++) {
                int k = p * 32 + kb + j;
                t8[j] = (k < KF) ? f2b(fval(d0, d1, d2, k)) : (bf16)0;
            }
            *(uint4*)&As[ar][kb] = *(const uint4*)t8;
#pragma unroll
            for (int i = 0; i < 4; i++) Bs[tid + i * 256] = WeP[(size_t)p * 1024 + tid + i * 256];
            __syncthreads();
            bf16x8 a = *(const bf16x8*)&As[16 * wv + m][quad * 8];
#pragma unroll
            for (int t = 0; t < 16; t++)
                acc1[t] = __builtin_amdgcn_mfma_f32_16x16x32_bf16(a, bfrag(bsu, t, m, quad),
                                                                  acc1[t], 0, 0, 0);
            __syncthreads();
        }
#pragma unroll
        for (int t = 0; t < 16; t++) {
            int col = t * 16 + m;
            float bias = be[col];
#pragma unroll
            for (int r = 0; r < 4; r++)
                heb[16 * wv + quad * 4 + r][col] = f2b(acc1[t][r] + bias);
        }
        __syncthreads();
    }

    f32x4 qa[16];
#pragma unroll
    for (int t = 0; t < 16; t++) qa[t] = (f32x4){0.f, 0.f, 0.f, 0.f};
    for (int p = 0; p < 16; p++) {
        if constexpr (HE) {
            const bf16* asrc = (p < 8) ? &hnb[(size_t)sid[ar] * 256 + p * 32 + kb]
                                       : &heG[(size_t)(e0 + ar) * 256 + (p - 8) * 32 + kb];
            *(uint4*)&As[ar][kb] = *(const uint4*)asrc;
        } else {
            if (p < 8)
                *(uint4*)&As[ar][kb] = *(const uint4*)&hnb[(size_t)sid[ar] * 256 + p * 32 + kb];
        }
#pragma unroll
        for (int i = 0; i < 4; i++) Bs[tid + i * 256] = QP[(size_t)p * 1024 + tid + i * 256];
        __syncthreads();
        bf16x8 a;
        if constexpr (HE)
            a = *(const bf16x8*)&As[16 * wv + m][quad * 8];
        else
            a = (p < 8) ? *(const bf16x8*)&As[16 * wv + m][quad * 8]
                        : *(const bf16x8*)&heb[16 * wv + m][(p - 8) * 32 + quad * 8];
#pragma unroll
        for (int t = 0; t < 16; t++)
            qa[t] = __builtin_amdgcn_mfma_f32_16x16x32_bf16(a, bfrag(bsu, t, m, quad),
                                                            qa[t], 0, 0, 0);
        __syncthreads();
    }
    f32x4 ka[16];
#pragma unroll
    for (int t = 0; t < 16; t++) ka[t] = (f32x4){0.f, 0.f, 0.f, 0.f};
    for (int p = 0; p < 16; p++) {
        if constexpr (HE) {
            const bf16* asrc = (p < 8) ? &hnb[(size_t)did[ar] * 256 + p * 32 + kb]
                                       : &heG[(size_t)(e0 + ar) * 256 + (p - 8) * 32 + kb];
            *(uint4*)&As[ar][kb] = *(const uint4*)asrc;
        } else {
            if (p < 8)
                *(uint4*)&As[ar][kb] = *(const uint4*)&hnb[(size_t)did[ar] * 256 + p * 32 + kb];
        }
#pragma unroll
        for (int i = 0; i < 4; i++) Bs[tid + i * 256] = KP[(size_t)p * 1024 + tid + i * 256];
        __syncthreads();
        bf16x8 a;
        if constexpr (HE)
            a = *(const bf16x8*)&As[16 * wv + m][quad * 8];
        else
            a = (p < 8) ? *(const bf16x8*)&As[16 * wv + m][quad * 8]
                        : *(const bf16x8*)&heb[16 * wv + m][(p - 8) * 32 + quad * 8];
#pragma unroll
        for (int t = 0; t < 16; t++)
            ka[t] = __builtin_amdgcn_mfma_f32_16x16x32_bf16(a, bfrag(bsu, t, m, quad),
                                                            ka[t], 0, 0, 0);
        __syncthreads();
    }
#pragma unroll
    for (int h = 0; h < 4; h++) {
        float p4[4];
#pragma unroll
        for (int r = 0; r < 4; r++) {
            float sum = 0.f;
#pragma unroll
            for (int ss = 0; ss < 4; ss++) {
                int t = h * 4 + ss;
                int col = t * 16 + m;
                sum += (qa[t][r] + bq[col]) * (ka[t][r] + bkv[col]);
            }
            p4[r] = sum;
        }
#pragma unroll
        for (int r = 0; r < 4; r++) {
            p4[r] += __shfl_xor(p4[r], 1, 64);
            p4[r] += __shfl_xor(p4[r], 2, 64);
            p4[r] += __shfl_xor(p4[r], 4, 64);
            p4[r] += __shfl_xor(p4[r], 8, 64);
        }
        if (m == 0) {
#pragma unroll
            for (int r = 0; r < 4; r++)
                scores[(size_t)(e0 + 16 * wv + quad * 4 + r) * 4 + h] = p4[r] * 0.125f;
        }
    }
}

// ---------------- MFMA AV kernel (fallback tier) ----------------

template <int HE>
__global__ void __launch_bounds__(256) k_av_mfma(
    const bf16* __restrict__ hnb, const int* __restrict__ src, const int* __restrict__ dst,
    const float* __restrict__ frac, const float* __restrict__ shifts,
    const uint4* __restrict__ WeP, const float* __restrict__ be,
    const bf16* __restrict__ heG,
    const uint4* __restrict__ VP, const float* __restrict__ bkv,
    const float* __restrict__ w, float* __restrict__ attn) {
    __shared__ bf16 heb[HE ? 1 : 64][HEPAD];
    __shared__ bf16 As[64][ASPAD];
    __shared__ uint4 Bs[1024];
    __shared__ float dsv[HE ? 1 : 64][3];
    __shared__ int sid[64], did[64];

    int tid = threadIdx.x;
    int wv = tid >> 6, lane = tid & 63, quad = lane >> 4, m = lane & 15;
    int e0 = blockIdx.x * 64;
    if (tid < 64) {
        int e = e0 + tid;
        int sn = src[e], dn = dst[e];
        sid[tid] = sn; did[tid] = dn;
        if constexpr (!HE) {
#pragma unroll
            for (int c = 0; c < 3; c++) {
                float a = frac[dn * 3 + c] - frac[sn * 3 + c] + shifts[e * 3 + c];
                dsv[tid][c] = a - floorf(a);
            }
        }
    }
    __syncthreads();

    int ar = tid >> 2, kb = (tid & 3) * 8;
    const bf16* bsu = (const bf16*)Bs;

    if constexpr (!HE) {
        float d0 = dsv[ar][0], d1 = dsv[ar][1], d2 = dsv[ar][2];
        f32x4 acc1[16];
#pragma unroll
        for (int t = 0; t < 16; t++) acc1[t] = (f32x4){0.f, 0.f, 0.f, 0.f};
        for (int p = 0; p < 19; p++) {
            bf16 t8[8];
#pragma unroll
            for (int j = 0; j < 8; j++) {
                int k = p * 32 + kb + j;
                t8[j] = (k < KF) ? f2b(fval(d0, d1, d2, k)) : (bf16)0;
            }
            *(uint4*)&As[ar][kb] = *(const uint4*)t8;
#pragma unroll
            for (int i = 0; i < 4; i++) Bs[tid + i * 256] = WeP[(size_t)p * 1024 + tid + i * 256];
            __syncthreads();
            bf16x8 a = *(const bf16x8*)&As[16 * wv + m][quad * 8];
#pragma unroll
            for (int t = 0; t < 16; t++)
                acc1[t] = __builtin_amdgcn_mfma_f32_16x16x32_bf16(a, bfrag(bsu, t, m, quad),
                                                                  acc1[t], 0, 0, 0);
            __syncthreads();
        }
#pragma unroll
        for (int t = 0; t < 16; t++) {
            int col = t * 16 + m;
            float bias = be[col];
#pragma unroll
            for (int r = 0; r < 4; r++)
                heb[16 * wv + quad * 4 + r][col] = f2b(acc1[t][r] + bias);
        }
        __syncthreads();
    }

    f32x4 va[16];
#pragma unroll
    for (int t = 0; t < 16; t++) va[t] = (f32x4){0.f, 0.f, 0.f, 0.f};
    for (int p = 0; p < 16; p++) {
        if constexpr (HE) {
            const bf16* asrc = (p < 8) ? &hnb[(size_t)did[ar] * 256 + p * 32 + kb]
                                       : &heG[(size_t)(e0 + ar) * 256 + (p - 8) * 32 + kb];
            *(uint4*)&As[ar][kb] = *(const uint4*)asrc;
        } else {
            if (p < 8)
                *(uint4*)&As[ar][kb] = *(const uint4*)&hnb[(size_t)did[ar] * 256 + p * 32 + kb];
        }
#pragma unroll
        for (int i = 0; i < 4; i++) Bs[tid + i * 256] = VP[(size_t)p * 1024 + tid + i * 256];
        __syncthreads();
        bf16x8 a;
        if constexpr (HE)
            a = *(const bf16x8*)&As[16 * wv + m][quad * 8];
        else
            a = (p < 8) ? *(const bf16x8*)&As[16 * wv + m][quad * 8]
                        : *(const bf16x8*)&heb[16 * wv + m][(p - 8) * 32 + quad * 8];
#pragma unroll
        for (int t = 0; t < 16; t++)
            va[t] = __builtin_amdgcn_mfma_f32_16x16x32_bf16(a, bfrag(bsu, t, m, quad),
                                                            va[t], 0, 0, 0);
        __syncthreads();
    }
    float wrow[4][4];
#pragma unroll
    for (int r = 0; r < 4; r++) {
        int e = e0 + 16 * wv + quad * 4 + r;
#pragma unroll
        for (int h = 0; h < 4; h++) wrow[r][h] = w[(size_t)e * 4 + h];
    }
#pragma unroll
    for (int t = 0; t < 16; t++) {
        int col = t * 16 + m;
        int h = t >> 2;
        float vb = bkv[256 + col];
#pragma unroll
        for (int r = 0; r < 4; r++) {
            int row = 16 * wv + quad * 4 + r;
            atomicAdd(&attn[(size_t)sid[row] * 256 + col], wrow[r][h] * (va[t][r] + vb));
        }
    }
}

// ---------------- node GEMM via MFMA (A-direct, B double-buffered) ----------------

template <int OUTB>
__global__ void __launch_bounds__(128) k_gnode(
    const bf16* __restrict__ Ab, int lda, const uint4* __restrict__ P, int ksteps,
    const float* __restrict__ bias, int act, float* __restrict__ Cf,
    bf16* __restrict__ Cb, int ldc) {
    __shared__ uint4 Bs[2][1024];
    int tid = threadIdx.x;
    int wv = tid >> 6, lane = tid & 63, quad = lane >> 4, m = lane & 15;
    int m0 = blockIdx.x * 32, g = blockIdx.y;
    const uint4* Pg = P + (size_t)g * ksteps * 1024;
    int arow = m0 + 16 * wv + m;
    f32x4 acc[16];
#pragma unroll
    for (int t = 0; t < 16; t++) acc[t] = (f32x4){0.f, 0.f, 0.f, 0.f};
#pragma unroll
    for (int i = 0; i < 8; i++) Bs[0][tid + i * 128] = Pg[tid + i * 128];
    __syncthreads();
    for (int p = 0; p < ksteps; p++) {
        if (p + 1 < ksteps) {
#pragma unroll
            for (int i = 0; i < 8; i++)
                Bs[(p + 1) & 1][tid + i * 128] = Pg[(size_t)(p + 1) * 1024 + tid + i * 128];
        }
        bf16x8 a = *(const bf16x8*)&Ab[(size_t)arow * lda + p * 32 + quad * 8];
        const bf16* bsu = (const bf16*)Bs[p & 1];
#pragma unroll
        for (int t = 0; t < 16; t++)
            acc[t] = __builtin_amdgcn_mfma_f32_16x16x32_bf16(a, bfrag(bsu, t, m, quad),
                                                             acc[t], 0, 0, 0);
        __syncthreads();
    }
#pragma unroll
    for (int t = 0; t < 16; t++) {
        int col = g * 256 + t * 16 + m;
        float bb = bias ? bias[col] : 0.f;
#pragma unroll
        for (int r = 0; r < 4; r++) {
            int row = m0 + 16 * wv + quad * 4 + r;
            float v = acc[t][r] + bb;
            if (act) v = 0.5f * v * (1.0f + erff(v * 0.7071067811865475f));
            if (OUTB) Cb[(size_t)row * ldc + col] = f2b(v);
            else Cf[(size_t)row * ldc + col] = v;
        }
    }
}

// ---------------- segment softmax (fallback tiers) ----------------

__global__ void k_softmax(const int* __restrict__ starts, const int* __restrict__ eids,
                          float* __restrict__ scores) {
    int n = blockIdx.x;
    int s0 = starts[n], s1 = starts[n + 1];
    int h = threadIdx.x >> 6, lane = threadIdx.x & 63;
    float mx = -1e30f;
    for (int i = s0 + lane; i < s1; i += 64) mx = fmaxf(mx, scores[eids[i] * 4 + h]);
    for (int m = 32; m >= 1; m >>= 1) mx = fmaxf(mx, __shfl_xor(mx, m, 64));
    float den = 0.f;
    for (int i = s0 + lane; i < s1; i += 64) den += __expf(scores[eids[i] * 4 + h] - mx);
    for (int m = 32; m >= 1; m >>= 1) den += __shfl_xor(den, m, 64);
    float inv = 1.0f / den;
    for (int i = s0 + lane; i < s1; i += 64) {
        int e = eids[i];
        scores[e * 4 + h] = __expf(scores[e * 4 + h] - mx) * inv;
    }
}

// ---------------- residual + layernorm (fallback tiers) ----------------

__global__ void k_add_ln(float* __restrict__ h, const float* __restrict__ r,
                         const float* __restrict__ g, const float* __restrict__ b,
                         bf16* __restrict__ hb) {
    __shared__ float red[4];
    int n = blockIdx.x, d = threadIdx.x;
    float x = h[n * DD + d] + r[n * DD + d];
    float v = x;
    for (int m = 32; m >= 1; m >>= 1) v += __shfl_xor(v, m, 64);
    if ((d & 63) == 0) red[d >> 6] = v;
    __syncthreads();
    float mu = (red[0] + red[1] + red[2] + red[3]) * (1.0f / 256.0f);
    __syncthreads();
    float t = x - mu;
    v = t * t;
    for (int m = 32; m >= 1; m >>= 1) v += __shfl_xor(v, m, 64);
    if ((d & 63) == 0) red[d >> 6] = v;
    __syncthreads();
    float var = (red[0] + red[1] + red[2] + red[3]) * (1.0f / 256.0f);
    float out = t * rsqrtf(var + 1e-5f) * g[d] + b[d];
    h[n * DD + d] = out;
    hb[n * DD + d] = f2b(out);
}

__global__ void k_out(const float* __restrict__ h, float* __restrict__ out) {
    int i = blockIdx.x * 256 + threadIdx.x;
    if (i < NN * DD) out[i] = h[i];
}

// ---------------- launch ----------------

extern "C" void kernel_launch(void* const* d_in, const int* in_sizes, int n_in,
                              void* d_out, int out_size, void* d_ws, size_t ws_size,
                              hipStream_t stream) {
    const int* atom_types = (const int*)d_in[0];
    const float* lattices = (const float*)d_in[1];
    const float* frac = (const float*)d_in[2];
    const int* eidx = (const int*)d_in[3];
    const float* shifts = (const float*)d_in[4];
    const int* batch_ids = (const int*)d_in[5];
    const float* atom_emb = (const float*)d_in[6];
    const float* node_W = (const float*)d_in[7];
    const float* node_b = (const float*)d_in[8];
    const float* edge_W = (const float*)d_in[9];
    const float* edge_b = (const float*)d_in[10];
    const float* Wq = (const float*)d_in[11];
    const float* bq = (const float*)d_in[12];
    const float* Wkv = (const float*)d_in[13];
    const float* bkv = (const float*)d_in[14];
    const float* Wo = (const float*)d_in[15];
    const float* bo = (const float*)d_in[16];
    const float* ln1g = (const float*)d_in[17];
    const float* ln1b = (const float*)d_in[18];
    const float* W1 = (const float*)d_in[19];
    const float* b1 = (const float*)d_in[20];
    const float* W2 = (const float*)d_in[21];
    const float* b2w = (const float*)d_in[22];
    const float* ln2g = (const float*)d_in[23];
    const float* ln2b = (const float*)d_in[24];

    char* base = (char*)d_ws;
    size_t off = 0;
    auto alloc = [&](size_t bytes) -> void* {
        void* p = base + off;
        off = (off + bytes + 255) & ~(size_t)255;
        return p;
    };
    int* counts = (int*)alloc((size_t)NN * 4);
    int* cursor = (int*)alloc((size_t)NN * 4);
    int* starts = (int*)alloc((size_t)(NN + 1) * 4);
    int* eids = (int*)alloc((size_t)EE * 4);
    float* lfeat = (float*)alloc((size_t)BB * 6 * 4);
    float* h_n = (float*)alloc((size_t)NN * DD * 4);
    float* attn = (float*)alloc((size_t)NN * DD * 4);
    float* tmp = (float*)alloc((size_t)NN * DD * 4);
    float* scores = tmp;  // first EEP*4 floats; srcP/dstP after (disjoint; total 4.8MB < 8.2MB)
    int* srcP = (int*)(scores + (size_t)EEP * 4);
    int* dstP = srcP + EEP;
    bf16* hnb = (bf16*)alloc((size_t)NN * DD * 2);
    bf16* attnb = (bf16*)alloc((size_t)NN * DD * 2);
    bf16* h1b = (bf16*)alloc((size_t)NN * 1024 * 2);
    bf16* WeP = (bf16*)alloc((size_t)19 * 8192 * 2);
    bf16* QP = (bf16*)alloc((size_t)LL * 16 * 8192 * 2);
    bf16* KP = (bf16*)alloc((size_t)LL * 16 * 8192 * 2);
    bf16* VP = (bf16*)alloc((size_t)LL * 16 * 8192 * 2);
    bf16* WoP = (bf16*)alloc((size_t)LL * 8 * 8192 * 2);
    bf16* W1P = (bf16*)alloc((size_t)LL * 32 * 8192 * 2);
    bf16* W2P = (bf16*)alloc((size_t)LL * 32 * 8192 * 2);
    bf16* heG = (bf16*)alloc((size_t)EEP * DD * 2);  // 102.4 MB (+pad rows)
    size_t off_he = off;
    bf16* NPP = (bf16*)alloc((size_t)LL * 24 * 8192 * 2);  // node panels [l][q|k|v][8]
    bf16* EPP = (bf16*)alloc((size_t)LL * 24 * 8192 * 2);  // edge panels [l][q|k|v][8]
    float* nbias = (float*)alloc((size_t)LL * 768 * 4);
    float* nodeQKV = (float*)alloc((size_t)NN * 768 * 4);  // 24.6 MB
    size_t off_f1 = off;
    bf16* hacc = (bf16*)alloc((size_t)NN * 4 * 256 * 2);    // 16.4 MB
    bf16* VWoP = (bf16*)alloc((size_t)LL * 32 * 8192 * 2);  // 2.1 MB (bdV@Wo panels)
    size_t off_f3 = off;
    const bool useHe = (off_he <= ws_size);
    const bool useF1 = (off_f1 <= ws_size);
    const bool useF3 = (off_f3 <= ws_size);
    bf16* avnb = attnb;           // reuse slot (F3 path only)
    float* VWo_f = (float*)h1b;   // setup-time scratch aliased onto h1b (4.2 MB < 16.4 MB)

    const int* src = eidx;
    const int* dstpub = eidx + EE;

    k_lfeat<<<1, 96, 0, stream>>>(lattices, lfeat);
    k_zero<<<(NN + 255) / 256, 256, 0, stream>>>(counts, NN);
    k_count<<<(EE + 255) / 256, 256, 0, stream>>>(src, counts);
    k_scan<<<1, 256, 0, stream>>>(counts, starts, cursor);
    k_scatter<<<(EE + 255) / 256, 256, 0, stream>>>(src, dstpub, cursor, eids, srcP, dstP);
    if (useF3) k_padinit<<<1, 256, 0, stream>>>(srcP, dstP, heG);
    k_node_init<<<NN, 256, 0, stream>>>(atom_types, batch_ids, atom_emb, node_W, node_b,
                                        lfeat, h_n, hnb);

    k_panel<<<dim3(19, 1, 1), 256, 0, stream>>>(edge_W, 256, 0, 0, 0, KF, WeP, 19, 19);
    k_panel<<<dim3(8, LL, 1), 256, 0, stream>>>(Wo, 256, 0, 0, 256 * 256, 256, WoP, 8, 8);
    k_panel<<<dim3(8, LL, 4), 256, 0, stream>>>(W1, 1024, 0, 0, 256 * 1024, 256, W1P, 8, 32);
    k_panel<<<dim3(32, LL, 1), 256, 0, stream>>>(W2, 256, 0, 0, 1024 * 256, 1024, W2P, 32, 32);

    if (useF1) {
        k_panel<<<dim3(8, LL, 1), 256, 0, stream>>>(Wq, 256, 0, 0, 512 * 256, 256, NPP, 8, 24);
        k_panel<<<dim3(8, LL, 1), 256, 0, stream>>>(Wkv, 512, 0, 0, 512 * 512, 256,
                                                    NPP + 8 * 8192, 8, 24);
        k_panel<<<dim3(8, LL, 1), 256, 0, stream>>>(Wkv, 512, 0, 256, 512 * 512, 256,
                                                    NPP + 16 * 8192, 8, 24);
        k_panel<<<dim3(8, LL, 1), 256, 0, stream>>>(Wq, 256, 256, 0, 512 * 256, 256, EPP, 8, 24);
        k_panel<<<dim3(8, LL, 1), 256, 0, stream>>>(Wkv, 512, 256, 0, 512 * 512, 256,
                                                    EPP + 8 * 8192, 8, 24);
        k_panel<<<dim3(8, LL, 1), 256, 0, stream>>>(Wkv, 512, 256, 256, 512 * 512, 256,
                                                    EPP + 16 * 8192, 8, 24);
        k_catbias<<<LL, 768, 0, stream>>>(bq, bkv, nbias);
        if (useF3) {
            k_vwo<<<dim3(1024, LL), 256, 0, stream>>>(Wkv, Wo, VWo_f);
            k_panel<<<dim3(32, LL, 1), 256, 0, stream>>>(VWo_f, 256, 0, 0, 1024 * 256, 1024,
                                                         VWoP, 32, 32);
        }
    } else {
        k_panel<<<dim3(16, LL, 1), 256, 0, stream>>>(Wq, 256, 0, 0, 512 * 256, 512, QP, 16, 16);
        k_panel<<<dim3(16, LL, 1), 256, 0, stream>>>(Wkv, 512, 0, 0, 512 * 512, 512, KP, 16, 16);
        k_panel<<<dim3(16, LL, 1), 256, 0, stream>>>(Wkv, 512, 0, 256, 512 * 512, 512, VP, 16, 16);
    }

    if (useHe) {
        k_he<<<EE / 64, 256, 0, stream>>>(src, dstpub, useF3 ? eids : nullptr, frac,
                                          shifts, (const uint4*)WeP, edge_b, heG);
    }

    for (int l = 0; l < LL; l++) {
        const uint4* WoPl = (const uint4*)(WoP + (size_t)l * 8 * 8192);
        const uint4* W1Pl = (const uint4*)(W1P + (size_t)l * 32 * 8192);
        const uint4* W2Pl = (const uint4*)(W2P + (size_t)l * 32 * 8192);

        if (useF1 && useF3) {
            const uint4* EQPl = (const uint4*)(EPP + (size_t)l * 24 * 8192);
            const uint4* EKPl = (const uint4*)(EPP + (size_t)l * 24 * 8192 + 8 * 8192);
            const uint4* VWoPl = (const uint4*)(VWoP + (size_t)l * 32 * 8192);
            k_gnode<0><<<dim3(NN / 32, 3), 128, 0, stream>>>(
                hnb, 256, (const uint4*)(NPP + (size_t)l * 24 * 8192), 8,
                nbias + l * 768, 0, nodeQKV, nullptr, 768);
            k_qk3<<<EEP / 128, 512, 0, stream>>>(heG, srcP, dstP, nodeQKV, EQPl, EKPl,
                                                 scores);
            k_avfused<<<NN, 256, 0, stream>>>(starts, dstP, scores, heG, nodeQKV,
                                              hacc, avnb);
            k_gnode_ln<<<NN / 32, 128, 0, stream>>>(
                hacc, 1024, VWoPl, 32, avnb, 256, WoPl, 8,
                bo + l * 256, h_n, ln1g + l * 256, ln1b + l * 256, h_n, hnb);
            k_gnode<1><<<dim3(NN / 32, 4), 128, 0, stream>>>(hnb, 256, W1Pl, 8,
                                                             b1 + l * 1024, 1, nullptr,
                                                             h1b, 1024);
            float* outp = (l == LL - 1) ? (float*)d_out : h_n;
            k_gnode_ln<<<NN / 32, 128, 0, stream>>>(
                h1b, 1024, W2Pl, 32, nullptr, 0, nullptr, 0,
                b2w + l * 256, h_n, ln2g + l * 256, ln2b + l * 256, outp, hnb);
        } else if (useF1) {
            const uint4* EQPl = (const uint4*)(EPP + (size_t)l * 24 * 8192);
            const uint4* EKPl = (const uint4*)(EPP + (size_t)l * 24 * 8192 + 8 * 8192);
            const uint4* EVPl = (const uint4*)(EPP + (size_t)l * 24 * 8192 + 16 * 8192);
            k_gnode<0><<<dim3(NN / 32, 3), 128, 0, stream>>>(
                hnb, 256, (const uint4*)(NPP + (size_t)l * 24 * 8192), 8,
                nbias + l * 768, 0, nodeQKV, nullptr, 768);
            k_qk2<<<EE / 64, 256, 0, stream>>>(heG, src, dstpub, nodeQKV, EQPl, EKPl,
                                               scores);
            k_softmax<<<NN, 256, 0, stream>>>(starts, eids, scores);
            k_zerof<<<(NN * DD + 255) / 256, 256, 0, stream>>>(attn, NN * DD);
            k_av3<<<EE / 64, 256, 0, stream>>>(heG, src, dstpub, nodeQKV, EVPl, scores,
                                               attn);
            k_cvt<<<(NN * DD + 255) / 256, 256, 0, stream>>>(attn, attnb, NN * DD);
            k_gnode<0><<<dim3(NN / 32, 1), 128, 0, stream>>>(attnb, 256, WoPl, 8,
                                                             bo + l * 256, 0, tmp, nullptr,
                                                             256);
            k_add_ln<<<NN, 256, 0, stream>>>(h_n, tmp, ln1g + l * 256, ln1b + l * 256, hnb);
            k_gnode<1><<<dim3(NN / 32, 4), 128, 0, stream>>>(hnb, 256, W1Pl, 8,
                                                             b1 + l * 1024, 1, nullptr,
                                                             h1b, 1024);
            k_gnode<0><<<dim3(NN / 32, 1), 128, 0, stream>>>(h1b, 1024, W2Pl, 32,
                                                             b2w + l * 256, 0, tmp, nullptr,
                                                             256);
            k_add_ln<<<NN, 256, 0, stream>>>(h_n, tmp, ln2g + l * 256, ln2b + l * 256, hnb);
        } else {
            const uint4* QPl = (const uint4*)(QP + (size_t)l * 16 * 8192);
            const uint4* KPl = (const uint4*)(KP + (size_t)l * 16 * 8192);
            const uint4* VPl = (const uint4*)(VP + (size_t)l * 16 * 8192);
            const float* bql = bq + l * 256;
            const float* bkvl = bkv + l * 512;
            if (useHe)
                k_qk_mfma<1><<<EE / 64, 256, 0, stream>>>(hnb, src, dstpub, frac, shifts,
                                                          (const uint4*)WeP, edge_b, heG,
                                                          QPl, KPl, bql, bkvl, scores);
            else
                k_qk_mfma<0><<<EE / 64, 256, 0, stream>>>(hnb, src, dstpub, frac, shifts,
                                                          (const uint4*)WeP, edge_b, nullptr,
                                                          QPl, KPl, bql, bkvl, scores);
            k_softmax<<<NN, 256, 0, stream>>>(starts, eids, scores);
            k_zerof<<<(NN * DD + 255) / 256, 256, 0, stream>>>(attn, NN * DD);
            if (useHe)
                k_av_mfma<1><<<EE / 64, 256, 0, stream>>>(hnb, src, dstpub, frac, shifts,
                                                          (const uint4*)WeP, edge_b, heG,
                                                          VPl, bkvl, scores, attn);
            else
                k_av_mfma<0><<<EE / 64, 256, 0, stream>>>(hnb, src, dstpub, frac, shifts,
                                                          (const uint4*)WeP, edge_b, nullptr,
                                                          VPl, bkvl, scores, attn);
            k_cvt<<<(NN * DD + 255) / 256, 256, 0, stream>>>(attn, attnb, NN * DD);
            k_gnode<0><<<dim3(NN / 32, 1), 128, 0, stream>>>(attnb, 256, WoPl, 8,
                                                             bo + l * 256, 0, tmp, nullptr,
                                                             256);
            k_add_ln<<<NN, 256, 0, stream>>>(h_n, tmp, ln1g + l * 256, ln1b + l * 256, hnb);
            k_gnode<1><<<dim3(NN / 32, 4), 128, 0, stream>>>(hnb, 256, W1Pl, 8,
                                                             b1 + l * 1024, 1, nullptr,
                                                             h1b, 1024);
            k_gnode<0><<<dim3(NN / 32, 1), 128, 0, stream>>>(h1b, 1024, W2Pl, 32,
                                                             b2w + l * 256, 0, tmp, nullptr,
                                                             256);
            k_add_ln<<<NN, 256, 0, stream>>>(h_n, tmp, ln2g + l * 256, ln2b + l * 256, hnb);
        }
    }
    if (!(useF1 && useF3))
        k_out<<<(NN * DD + 255) / 256, 256, 0, stream>>>(h_n, (float*)d_out);
}